// Round 2
// baseline (1122.156 us; speedup 1.0000x reference)
//
#include <hip/hip_runtime.h>
#include <stdint.h>

#define N_NODES 131072
#define N_EDGES 2097152
#define NG 64
#define D_INF 64
#define HD 128
#define NL 3
#define EPSB 1e-5f

typedef unsigned short ushort_t;
typedef __bf16 bf16x8 __attribute__((ext_vector_type(8)));
typedef float f32x4 __attribute__((ext_vector_type(4)));

__device__ __forceinline__ float bf2f(uint32_t u16) {
    union { uint32_t i; float f; } c; c.i = u16 << 16; return c.f;
}
__device__ __forceinline__ float lo2f(uint32_t u) {
    union { uint32_t i; float f; } c; c.i = u << 16; return c.f;
}
__device__ __forceinline__ float hi2f(uint32_t u) {
    union { uint32_t i; float f; } c; c.i = u & 0xffff0000u; return c.f;
}
__device__ __forceinline__ ushort_t f2bf(float f) {
    union { float f; uint32_t i; } c; c.f = f;
    uint32_t u = c.i;
    uint32_t r = (u + 0x7fffu + ((u >> 16) & 1u)) >> 16;
    return (ushort_t)r;
}
// dtype-adaptive scalar load: isb=1 -> bf16 array, isb=0 -> fp32 array
__device__ __forceinline__ float ldf(const void* p, int i, int isb) {
    return isb ? bf2f(((const ushort_t*)p)[i]) : ((const float*)p)[i];
}

// ---------------- dtype sniffer on edge_attr_raw
// bf16 data: both 16-bit halves of each word have exponent ~[120,132] (N(0,1)).
// fp32 data: low half is mantissa bits -> ~16% plausible. Vote with 90% bar.
__global__ void detect_k(const uint32_t* __restrict__ ea, int* __restrict__ flag) {
    __shared__ int sm[256];
    int t = threadIdx.x;
    int plaus = 0;
    for (int j = 0; j < 16; j++) {
        uint32_t w = ea[t * 16 + j];
        uint32_t e0 = (w >> 7) & 0xFF;
        uint32_t e1 = (w >> 23) & 0xFF;
        plaus += (e0 >= 100 && e0 <= 140) ? 1 : 0;
        plaus += (e1 >= 100 && e1 <= 140) ? 1 : 0;
    }
    sm[t] = plaus;
    __syncthreads();
    for (int o = 128; o > 0; o >>= 1) {
        if (t < o) sm[t] += sm[t + o];
        __syncthreads();
    }
    if (t == 0) flag[0] = (sm[0] * 10 >= 8192 * 9) ? 1 : 0;
}

// ---------------- BN fold: sc = gamma/sqrt(var+eps), sh = (b_gcn-mean)*sc+beta
__global__ void prep_bn(const void* gamma, const void* beta,
                        const void* mean, const void* var,
                        const void* bgcn, float* sc, float* sh,
                        const int* __restrict__ flag) {
    int isb = flag[0];
    int i = blockIdx.x * 128 + threadIdx.x;
    if (i < NL * HD) {
        float g = ldf(gamma, i, isb), b = ldf(beta, i, isb);
        float m = ldf(mean, i, isb), v = ldf(var, i, isb), bb = ldf(bgcn, i, isb);
        float s = g / sqrtf(v + EPSB);
        sc[i] = s;
        sh[i] = (bb - m) * s + b;
    }
}

// ---------------- CSR build
__global__ void hist_k(const int* __restrict__ row, int* __restrict__ cnt) {
    int e = blockIdx.x * 256 + threadIdx.x;
    if (e < N_EDGES) atomicAdd(&cnt[row[e]], 1);
}

__global__ void scan_k(const int* __restrict__ cnt, int* __restrict__ off) {
    __shared__ int sm[1024];
    int t = threadIdx.x;
    int base = t * 128;
    int s = 0;
#pragma unroll 4
    for (int j = 0; j < 128; j++) s += cnt[base + j];
    sm[t] = s;
    __syncthreads();
    for (int o = 1; o < 1024; o <<= 1) {
        int v = (t >= o) ? sm[t - o] : 0;
        __syncthreads();
        sm[t] += v;
        __syncthreads();
    }
    int run = sm[t] - s;  // exclusive prefix of this chunk
    for (int j = 0; j < 128; j++) { off[base + j] = run; run += cnt[base + j]; }
}

// canonicalizes edge attrs into packed-bf16 u32 regardless of input dtype
__global__ void scatter_k(const int* __restrict__ row, const int* __restrict__ col,
                          const void* __restrict__ ea_raw,
                          const int* __restrict__ off, int* __restrict__ cursor,
                          int* __restrict__ csr_col, uint32_t* __restrict__ csr_ea,
                          const int* __restrict__ flag) {
    int isb = flag[0];
    int e = blockIdx.x * 256 + threadIdx.x;
    if (e < N_EDGES) {
        int r = row[e];
        int pos = off[r] + atomicAdd(&cursor[r], 1);
        csr_col[pos] = col[e];
        uint32_t packed;
        if (isb) {
            packed = ((const uint32_t*)ea_raw)[e];
        } else {
            const float* f = (const float*)ea_raw + e * 2;
            packed = (uint32_t)f2bf(f[0]) | ((uint32_t)f2bf(f[1]) << 16);
        }
        csr_ea[pos] = packed;
    }
}

// ---------------- aggregate: one wave per node. t[n] = h[n] + (sum_e h[col]*ea)/deg
__global__ __launch_bounds__(256) void aggregate_k(
    const uint32_t* __restrict__ h32,      // internal h as [N, 64] u32 (bf16x2)
    const int* __restrict__ csr_off, const int* __restrict__ cnt,
    const int* __restrict__ csr_col, const uint32_t* __restrict__ csr_ea,
    const void* __restrict__ Wedge,        // [2,128]
    const void* __restrict__ bedge,        // [128]
    uint32_t* __restrict__ t32,            // out [N,64] u32
    const int* __restrict__ flag)
{
    int isb = flag[0];
    int lane = threadIdx.x & 63;
    int node = __builtin_amdgcn_readfirstlane(blockIdx.x * 4 + (threadIdx.x >> 6));

    float w0x = ldf(Wedge, 2 * lane, isb),       w0y = ldf(Wedge, 2 * lane + 1, isb);
    float w1x = ldf(Wedge, 128 + 2 * lane, isb), w1y = ldf(Wedge, 128 + 2 * lane + 1, isb);
    float bex = ldf(bedge, 2 * lane, isb),       bey = ldf(bedge, 2 * lane + 1, isb);

    int start = csr_off[node];
    int deg = cnt[node];
    float ax = 0.f, ay = 0.f;
    for (int i = 0; i < deg; i++) {
        int c = csr_col[start + i];
        uint32_t av = csr_ea[start + i];
        float a0 = bf2f(av & 0xffffu);
        float a1 = bf2f(av >> 16);
        uint32_t hv = h32[c * 64 + lane];
        float eax = a0 * w0x + a1 * w1x + bex;
        float eay = a0 * w0y + a1 * w1y + bey;
        ax += lo2f(hv) * eax;
        ay += hi2f(hv) * eay;
    }
    float inv = 1.0f / (float)(deg > 0 ? deg : 1);
    uint32_t hn = h32[node * 64 + lane];
    float tx = lo2f(hn) + ax * inv;
    float ty = hi2f(hn) + ay * inv;
    t32[node * 64 + lane] = (uint32_t)f2bf(tx) | ((uint32_t)f2bf(ty) << 16);
}

// ---------------- GEMM: h0 = x @ W_in + b_in   ([N,64]x[64,128]) -> internal bf16
__global__ __launch_bounds__(256) void gemm_in_k(
    const void* __restrict__ X, const void* __restrict__ W,
    const void* __restrict__ bin, ushort_t* __restrict__ Hout,
    const int* __restrict__ flag)
{
    __shared__ ushort_t WT[128 * 72];  // WT[n][k], pad 72
    int isb = flag[0];
    int tid = threadIdx.x;
    for (int idx = tid; idx < 64 * 128; idx += 256) {
        int k = idx >> 7, n = idx & 127;
        WT[n * 72 + k] = f2bf(ldf(W, idx, isb));
    }
    __syncthreads();
    int wave = tid >> 6, lane = tid & 63;
    int quad = lane >> 4, l16 = lane & 15;
    int row = blockIdx.x * 64 + wave * 16 + l16;

    f32x4 acc[8];
#pragma unroll
    for (int c = 0; c < 8; c++) acc[c] = (f32x4){0.f, 0.f, 0.f, 0.f};

#pragma unroll
    for (int kk = 0; kk < 2; kk++) {
        int aoff = row * 64 + kk * 32 + quad * 8;
        union { bf16x8 v; ushort_t s[8]; } a;
        if (isb) {
            a.v = *(const bf16x8*)((const ushort_t*)X + aoff);
        } else {
            const float* xf = (const float*)X + aoff;
            f32x4 p0 = *(const f32x4*)xf;
            f32x4 p1 = *(const f32x4*)(xf + 4);
#pragma unroll
            for (int j = 0; j < 4; j++) { a.s[j] = f2bf(p0[j]); a.s[4 + j] = f2bf(p1[j]); }
        }
#pragma unroll
        for (int c = 0; c < 8; c++) {
            bf16x8 b = *(const bf16x8*)(&WT[(c * 16 + l16) * 72 + kk * 32 + quad * 8]);
            acc[c] = __builtin_amdgcn_mfma_f32_16x16x32_bf16(a.v, b, acc[c], 0, 0, 0);
        }
    }
    int rbase = blockIdx.x * 64 + wave * 16 + quad * 4;
#pragma unroll
    for (int c = 0; c < 8; c++) {
        int gcol = c * 16 + l16;
        float bb = ldf(bin, gcol, isb);
#pragma unroll
        for (int r = 0; r < 4; r++) {
            Hout[(rbase + r) * 128 + gcol] = f2bf(acc[c][r] + bb);
        }
    }
}

// ---------------- GEMM + BN + ReLU: h = relu((t @ W)*sc + sh)  ([N,128]x[128,128])
__global__ __launch_bounds__(256) void gemm_layer_k(
    const ushort_t* __restrict__ T, const void* __restrict__ W,
    const float* __restrict__ sc, const float* __restrict__ sh,
    ushort_t* __restrict__ Hout, const int* __restrict__ flag)
{
    __shared__ ushort_t WT[128 * 136];  // WT[n][k], pad 136
    int isb = flag[0];
    int tid = threadIdx.x;
    for (int idx = tid; idx < 128 * 128; idx += 256) {
        int k = idx >> 7, n = idx & 127;
        WT[n * 136 + k] = f2bf(ldf(W, idx, isb));
    }
    __syncthreads();
    int wave = tid >> 6, lane = tid & 63;
    int quad = lane >> 4, l16 = lane & 15;
    int row = blockIdx.x * 64 + wave * 16 + l16;

    f32x4 acc[8];
#pragma unroll
    for (int c = 0; c < 8; c++) acc[c] = (f32x4){0.f, 0.f, 0.f, 0.f};

#pragma unroll
    for (int kk = 0; kk < 4; kk++) {
        bf16x8 a = *(const bf16x8*)(T + row * 128 + kk * 32 + quad * 8);
#pragma unroll
        for (int c = 0; c < 8; c++) {
            bf16x8 b = *(const bf16x8*)(&WT[(c * 16 + l16) * 136 + kk * 32 + quad * 8]);
            acc[c] = __builtin_amdgcn_mfma_f32_16x16x32_bf16(a, b, acc[c], 0, 0, 0);
        }
    }
    int rbase = blockIdx.x * 64 + wave * 16 + quad * 4;
#pragma unroll
    for (int c = 0; c < 8; c++) {
        int gcol = c * 16 + l16;
        float s = sc[gcol], o = sh[gcol];
#pragma unroll
        for (int r = 0; r < 4; r++) {
            float v = acc[c][r] * s + o;
            v = fmaxf(v, 0.f);
            Hout[(rbase + r) * 128 + gcol] = f2bf(v);
        }
    }
}

// ---------------- pool: batch is sorted; flush-on-change running sums
__global__ __launch_bounds__(128) void pool_k(
    const ushort_t* __restrict__ Hf, const int* __restrict__ batch,
    float* __restrict__ gsum, int* __restrict__ gcnt)
{
    int t = threadIdx.x;            // feature
    int n0 = blockIdx.x * 256;      // 512 blocks x 256 nodes
    int n1 = n0 + 256;
    int cur = batch[n0];
    float s = 0.f; int c = 0;
    for (int n = n0; n < n1; n++) {
        int g = batch[n];
        if (g != cur) {
            atomicAdd(&gsum[cur * 128 + t], s);
            if (t == 0) atomicAdd(&gcnt[cur], c);
            s = 0.f; c = 0; cur = g;
        }
        s += bf2f(Hf[n * 128 + t]);
        c++;
    }
    atomicAdd(&gsum[cur * 128 + t], s);
    if (t == 0) atomicAdd(&gcnt[cur], c);
}

// ---------------- final: out = concat(g, relu(gx@Wgp+bgp)) @ Wgc + bgc
__global__ __launch_bounds__(128) void final_k(
    const float* __restrict__ gsum, const int* __restrict__ gcnt,
    const void* __restrict__ gx, const void* __restrict__ Wgp,
    const void* __restrict__ bgp, const void* __restrict__ Wgc,
    const void* __restrict__ bgc, void* __restrict__ out,
    const int* __restrict__ flag)
{
    __shared__ float gm[160];
    int isb = flag[0];
    int g = blockIdx.x, t = threadIdx.x;
    int c = gcnt[g]; if (c < 1) c = 1;
    gm[t] = gsum[g * 128 + t] / (float)c;
    if (t < 32) {
        float a = ldf(bgp, t, isb);
        for (int d = 0; d < 6; d++) a += ldf(gx, g * 6 + d, isb) * ldf(Wgp, d * 32 + t, isb);
        gm[128 + t] = fmaxf(a, 0.f);
    }
    __syncthreads();
    float a = ldf(bgc, t, isb);
    for (int k = 0; k < 160; k++) a += gm[k] * ldf(Wgc, k * 128 + t, isb);
    if (isb) ((ushort_t*)out)[g * 128 + t] = f2bf(a);
    else     ((float*)out)[g * 128 + t] = a;
}

extern "C" void kernel_launch(void* const* d_in, const int* in_sizes, int n_in,
                              void* d_out, int out_size, void* d_ws, size_t ws_size,
                              hipStream_t stream) {
    const void* x       = d_in[0];
    const void* ea_raw  = d_in[1];
    const void* gx      = d_in[2];
    const void* W_in    = d_in[3];
    const void* b_in    = d_in[4];
    const void* W_edge  = d_in[5];
    const void* b_edge  = d_in[6];
    const void* W_gcn   = d_in[7];
    const void* bn_g    = d_in[9];
    const void* bn_b    = d_in[10];
    const void* bn_m    = d_in[11];
    const void* bn_v    = d_in[12];
    const void* b_gcn   = d_in[8];
    const void* W_gproj = d_in[13];
    const void* b_gproj = d_in[14];
    const void* W_gcomb = d_in[15];
    const void* b_gcomb = d_in[16];
    const int* row   = (const int*)d_in[17];
    const int* col   = (const int*)d_in[18];
    const int* batch = (const int*)d_in[19];

    char* ws = (char*)d_ws;
    size_t off = 0;
    int*      cnt     = (int*)(ws + off);      off += (size_t)N_NODES * 4;
    int*      cursor  = (int*)(ws + off);      off += (size_t)N_NODES * 4;
    float*    gsum    = (float*)(ws + off);    off += (size_t)NG * HD * 4;
    int*      gcnt    = (int*)(ws + off);      off += 256;
    size_t zero_bytes = off;                    // [cnt|cursor|gsum|gcnt]
    int*      flag    = (int*)(ws + off);      off += 256;
    int*      csr_off = (int*)(ws + off);      off += (size_t)N_NODES * 4;
    int*      csr_col = (int*)(ws + off);      off += (size_t)N_EDGES * 4;
    uint32_t* csr_ea  = (uint32_t*)(ws + off); off += (size_t)N_EDGES * 4;
    ushort_t* hbuf    = (ushort_t*)(ws + off); off += (size_t)N_NODES * HD * 2;
    ushort_t* tbuf    = (ushort_t*)(ws + off); off += (size_t)N_NODES * HD * 2;
    float*    sc      = (float*)(ws + off);    off += (size_t)NL * HD * 4;
    float*    sh      = (float*)(ws + off);    off += (size_t)NL * HD * 4;

    hipMemsetAsync(ws, 0, zero_bytes, stream);
    detect_k<<<1, 256, 0, stream>>>((const uint32_t*)ea_raw, flag);
    prep_bn<<<3, 128, 0, stream>>>(bn_g, bn_b, bn_m, bn_v, b_gcn, sc, sh, flag);
    hist_k<<<N_EDGES / 256, 256, 0, stream>>>(row, cnt);
    scan_k<<<1, 1024, 0, stream>>>(cnt, csr_off);
    scatter_k<<<N_EDGES / 256, 256, 0, stream>>>(row, col, ea_raw, csr_off, cursor,
                                                 csr_col, csr_ea, flag);
    gemm_in_k<<<N_NODES / 64, 256, 0, stream>>>(x, W_in, b_in, hbuf, flag);

    for (int l = 0; l < NL; l++) {
        aggregate_k<<<N_NODES / 4, 256, 0, stream>>>(
            (const uint32_t*)hbuf, csr_off, cnt, csr_col, csr_ea,
            W_edge, b_edge, (uint32_t*)tbuf, flag);
        gemm_layer_k<<<N_NODES / 64, 256, 0, stream>>>(
            tbuf, (const char*)W_gcn + (size_t)l * HD * HD * 4, sc + l * HD, sh + l * HD,
            hbuf, flag);
    }

    pool_k<<<N_NODES / 256, 128, 0, stream>>>(hbuf, batch, gsum, gcnt);
    final_k<<<NG, 128, 0, stream>>>(gsum, gcnt, gx, W_gproj, b_gproj,
                                    W_gcomb, b_gcomb, d_out, flag);
}

// Round 3
// 881.022 us; speedup vs baseline: 1.2737x; 1.2737x over previous
//
#include <hip/hip_runtime.h>
#include <stdint.h>

#define N_NODES 131072
#define N_EDGES 2097152
#define NG 64
#define HD 128
#define NL 3
#define EPSB 1e-5f
// padded CSR capacity: sum of pad8(deg) <= E + 7N
#define CSR_CAP (N_EDGES + 7 * N_NODES)

typedef unsigned short ushort_t;
typedef __bf16 bf16x8 __attribute__((ext_vector_type(8)));
typedef float f32x4 __attribute__((ext_vector_type(4)));

__device__ __forceinline__ float bf2f(uint32_t u16) {
    union { uint32_t i; float f; } c; c.i = u16 << 16; return c.f;
}
__device__ __forceinline__ float lo2f(uint32_t u) {
    union { uint32_t i; float f; } c; c.i = u << 16; return c.f;
}
__device__ __forceinline__ float hi2f(uint32_t u) {
    union { uint32_t i; float f; } c; c.i = u & 0xffff0000u; return c.f;
}
__device__ __forceinline__ ushort_t f2bf(float f) {
    union { float f; uint32_t i; } c; c.f = f;
    uint32_t u = c.i;
    uint32_t r = (u + 0x7fffu + ((u >> 16) & 1u)) >> 16;
    return (ushort_t)r;
}
// dtype-adaptive scalar load: isb=1 -> bf16 array, isb=0 -> fp32 array
__device__ __forceinline__ float ldf(const void* p, int i, int isb) {
    return isb ? bf2f(((const ushort_t*)p)[i]) : ((const float*)p)[i];
}

// ---------------- dtype sniffer on edge_attr_raw
__global__ void detect_k(const uint32_t* __restrict__ ea, int* __restrict__ flag) {
    __shared__ int sm[256];
    int t = threadIdx.x;
    int plaus = 0;
    for (int j = 0; j < 16; j++) {
        uint32_t w = ea[t * 16 + j];
        uint32_t e0 = (w >> 7) & 0xFF;
        uint32_t e1 = (w >> 23) & 0xFF;
        plaus += (e0 >= 100 && e0 <= 140) ? 1 : 0;
        plaus += (e1 >= 100 && e1 <= 140) ? 1 : 0;
    }
    sm[t] = plaus;
    __syncthreads();
    for (int o = 128; o > 0; o >>= 1) {
        if (t < o) sm[t] += sm[t + o];
        __syncthreads();
    }
    if (t == 0) flag[0] = (sm[0] * 10 >= 8192 * 9) ? 1 : 0;
}

// ---------------- BN fold
__global__ void prep_bn(const void* gamma, const void* beta,
                        const void* mean, const void* var,
                        const void* bgcn, float* sc, float* sh,
                        const int* __restrict__ flag) {
    int isb = flag[0];
    int i = blockIdx.x * 128 + threadIdx.x;
    if (i < NL * HD) {
        float g = ldf(gamma, i, isb), b = ldf(beta, i, isb);
        float m = ldf(mean, i, isb), v = ldf(var, i, isb), bb = ldf(bgcn, i, isb);
        float s = g / sqrtf(v + EPSB);
        sc[i] = s;
        sh[i] = (bb - m) * s + b;
    }
}

// ---------------- CSR build
__global__ void hist_k(const int* __restrict__ row, int* __restrict__ cnt) {
    int e = blockIdx.x * 256 + threadIdx.x;
    if (e < N_EDGES) atomicAdd(&cnt[row[e]], 1);
}

// offsets over PADDED counts (pad8), so every segment start is 64B-aligned
__global__ void scan_k(const int* __restrict__ cnt, int* __restrict__ off) {
    __shared__ int sm[1024];
    int t = threadIdx.x;
    int base = t * 128;
    int s = 0;
#pragma unroll 4
    for (int j = 0; j < 128; j++) s += (cnt[base + j] + 7) & ~7;
    sm[t] = s;
    __syncthreads();
    for (int o = 1; o < 1024; o <<= 1) {
        int v = (t >= o) ? sm[t - o] : 0;
        __syncthreads();
        sm[t] += v;
        __syncthreads();
    }
    int run = sm[t] - s;
    for (int j = 0; j < 128; j++) {
        off[base + j] = run;
        run += (cnt[base + j] + 7) & ~7;
    }
}

// fill whole padded CSR with sentinel {col=N_NODES (zero dummy row), ea=0}
__global__ void fill_k(uint4* __restrict__ csr4) {
    int i = blockIdx.x * 256 + threadIdx.x;   // each uint4 = 2 entries
    if (i < CSR_CAP / 2) {
        csr4[i] = make_uint4(N_NODES, 0u, N_NODES, 0u);
    }
}

// canonicalize edge attrs into packed-bf16, one 8B store per edge
__global__ void scatter_k(const int* __restrict__ row, const int* __restrict__ col,
                          const void* __restrict__ ea_raw,
                          const int* __restrict__ off, int* __restrict__ cursor,
                          uint2* __restrict__ csr, const int* __restrict__ flag) {
    int isb = flag[0];
    int e = blockIdx.x * 256 + threadIdx.x;
    if (e < N_EDGES) {
        int r = row[e];
        uint32_t packed;
        if (isb) {
            packed = ((const uint32_t*)ea_raw)[e];
        } else {
            const float* f = (const float*)ea_raw + e * 2;
            packed = (uint32_t)f2bf(f[0]) | ((uint32_t)f2bf(f[1]) << 16);
        }
        int pos = off[r] + atomicAdd(&cursor[r], 1);
        csr[pos] = make_uint2((uint32_t)col[e], packed);
    }
}

// ---------------- aggregate: one wave per node, 8 gathers in flight
__global__ __launch_bounds__(256) void aggregate_k(
    const uint32_t* __restrict__ h32,      // [N+1, 64] u32 (bf16x2), row N zeroed
    const int* __restrict__ csr_off, const int* __restrict__ cnt,
    const uint2* __restrict__ csr,
    const void* __restrict__ Wedge,        // [2,128]
    const void* __restrict__ bedge,        // [128]
    uint32_t* __restrict__ t32,            // out [N,64] u32
    const int* __restrict__ flag)
{
    int isb = flag[0];
    int lane = threadIdx.x & 63;
    int node = __builtin_amdgcn_readfirstlane(blockIdx.x * 4 + (threadIdx.x >> 6));

    float w0x = ldf(Wedge, 2 * lane, isb),       w0y = ldf(Wedge, 2 * lane + 1, isb);
    float w1x = ldf(Wedge, 128 + 2 * lane, isb), w1y = ldf(Wedge, 128 + 2 * lane + 1, isb);
    float bex = ldf(bedge, 2 * lane, isb),       bey = ldf(bedge, 2 * lane + 1, isb);

    int start = csr_off[node];          // multiple of 8 entries (64B aligned)
    int deg = cnt[node];
    int iters = (deg + 7) >> 3;
    const uint4* seg = (const uint4*)(csr + start);   // 2 edges per uint4

    float ax = 0.f, ay = 0.f;
    for (int it = 0; it < iters; it++) {
        uint4 q0 = seg[it * 4 + 0];
        uint4 q1 = seg[it * 4 + 1];
        uint4 q2 = seg[it * 4 + 2];
        uint4 q3 = seg[it * 4 + 3];
        uint32_t cols[8] = {q0.x, q0.z, q1.x, q1.z, q2.x, q2.z, q3.x, q3.z};
        uint32_t eav[8]  = {q0.y, q0.w, q1.y, q1.w, q2.y, q2.w, q3.y, q3.w};
        uint32_t hv[8];
#pragma unroll
        for (int j = 0; j < 8; j++) hv[j] = h32[cols[j] * 64 + lane];
#pragma unroll
        for (int j = 0; j < 8; j++) {
            float a0 = bf2f(eav[j] & 0xffffu);
            float a1 = bf2f(eav[j] >> 16);
            float eax = a0 * w0x + a1 * w1x + bex;
            float eay = a0 * w0y + a1 * w1y + bey;
            ax += lo2f(hv[j]) * eax;
            ay += hi2f(hv[j]) * eay;
        }
    }
    float inv = 1.0f / (float)(deg > 0 ? deg : 1);
    uint32_t hn = h32[node * 64 + lane];
    float tx = lo2f(hn) + ax * inv;
    float ty = hi2f(hn) + ay * inv;
    t32[node * 64 + lane] = (uint32_t)f2bf(tx) | ((uint32_t)f2bf(ty) << 16);
}

// ---------------- GEMM: h0 = x @ W_in + b_in   ([N,64]x[64,128]) -> internal bf16
__global__ __launch_bounds__(256) void gemm_in_k(
    const void* __restrict__ X, const void* __restrict__ W,
    const void* __restrict__ bin, ushort_t* __restrict__ Hout,
    const int* __restrict__ flag)
{
    __shared__ ushort_t WT[128 * 72];
    int isb = flag[0];
    int tid = threadIdx.x;
    for (int idx = tid; idx < 64 * 128; idx += 256) {
        int k = idx >> 7, n = idx & 127;
        WT[n * 72 + k] = f2bf(ldf(W, idx, isb));
    }
    __syncthreads();
    int wave = tid >> 6, lane = tid & 63;
    int quad = lane >> 4, l16 = lane & 15;
    int row = blockIdx.x * 64 + wave * 16 + l16;

    f32x4 acc[8];
#pragma unroll
    for (int c = 0; c < 8; c++) acc[c] = (f32x4){0.f, 0.f, 0.f, 0.f};

#pragma unroll
    for (int kk = 0; kk < 2; kk++) {
        int aoff = row * 64 + kk * 32 + quad * 8;
        union { bf16x8 v; ushort_t s[8]; } a;
        if (isb) {
            a.v = *(const bf16x8*)((const ushort_t*)X + aoff);
        } else {
            const float* xf = (const float*)X + aoff;
            f32x4 p0 = *(const f32x4*)xf;
            f32x4 p1 = *(const f32x4*)(xf + 4);
#pragma unroll
            for (int j = 0; j < 4; j++) { a.s[j] = f2bf(p0[j]); a.s[4 + j] = f2bf(p1[j]); }
        }
#pragma unroll
        for (int c = 0; c < 8; c++) {
            bf16x8 b = *(const bf16x8*)(&WT[(c * 16 + l16) * 72 + kk * 32 + quad * 8]);
            acc[c] = __builtin_amdgcn_mfma_f32_16x16x32_bf16(a.v, b, acc[c], 0, 0, 0);
        }
    }
    int rbase = blockIdx.x * 64 + wave * 16 + quad * 4;
#pragma unroll
    for (int c = 0; c < 8; c++) {
        int gcol = c * 16 + l16;
        float bb = ldf(bin, gcol, isb);
#pragma unroll
        for (int r = 0; r < 4; r++) {
            Hout[(rbase + r) * 128 + gcol] = f2bf(acc[c][r] + bb);
        }
    }
}

// ---------------- GEMM + BN + ReLU: h = relu((t @ W)*sc + sh)
__global__ __launch_bounds__(256) void gemm_layer_k(
    const ushort_t* __restrict__ T, const void* __restrict__ W,
    const float* __restrict__ sc, const float* __restrict__ sh,
    ushort_t* __restrict__ Hout, const int* __restrict__ flag)
{
    __shared__ ushort_t WT[128 * 136];
    int isb = flag[0];
    int tid = threadIdx.x;
    for (int idx = tid; idx < 128 * 128; idx += 256) {
        int k = idx >> 7, n = idx & 127;
        WT[n * 136 + k] = f2bf(ldf(W, idx, isb));
    }
    __syncthreads();
    int wave = tid >> 6, lane = tid & 63;
    int quad = lane >> 4, l16 = lane & 15;
    int row = blockIdx.x * 64 + wave * 16 + l16;

    f32x4 acc[8];
#pragma unroll
    for (int c = 0; c < 8; c++) acc[c] = (f32x4){0.f, 0.f, 0.f, 0.f};

#pragma unroll
    for (int kk = 0; kk < 4; kk++) {
        bf16x8 a = *(const bf16x8*)(T + row * 128 + kk * 32 + quad * 8);
#pragma unroll
        for (int c = 0; c < 8; c++) {
            bf16x8 b = *(const bf16x8*)(&WT[(c * 16 + l16) * 136 + kk * 32 + quad * 8]);
            acc[c] = __builtin_amdgcn_mfma_f32_16x16x32_bf16(a, b, acc[c], 0, 0, 0);
        }
    }
    int rbase = blockIdx.x * 64 + wave * 16 + quad * 4;
#pragma unroll
    for (int c = 0; c < 8; c++) {
        int gcol = c * 16 + l16;
        float s = sc[gcol], o = sh[gcol];
#pragma unroll
        for (int r = 0; r < 4; r++) {
            float v = acc[c][r] * s + o;
            v = fmaxf(v, 0.f);
            Hout[(rbase + r) * 128 + gcol] = f2bf(v);
        }
    }
}

// ---------------- pool
__global__ __launch_bounds__(128) void pool_k(
    const ushort_t* __restrict__ Hf, const int* __restrict__ batch,
    float* __restrict__ gsum, int* __restrict__ gcnt)
{
    int t = threadIdx.x;
    int n0 = blockIdx.x * 256;
    int n1 = n0 + 256;
    int cur = batch[n0];
    float s = 0.f; int c = 0;
    for (int n = n0; n < n1; n++) {
        int g = batch[n];
        if (g != cur) {
            atomicAdd(&gsum[cur * 128 + t], s);
            if (t == 0) atomicAdd(&gcnt[cur], c);
            s = 0.f; c = 0; cur = g;
        }
        s += bf2f(Hf[n * 128 + t]);
        c++;
    }
    atomicAdd(&gsum[cur * 128 + t], s);
    if (t == 0) atomicAdd(&gcnt[cur], c);
}

// ---------------- final
__global__ __launch_bounds__(128) void final_k(
    const float* __restrict__ gsum, const int* __restrict__ gcnt,
    const void* __restrict__ gx, const void* __restrict__ Wgp,
    const void* __restrict__ bgp, const void* __restrict__ Wgc,
    const void* __restrict__ bgc, void* __restrict__ out,
    const int* __restrict__ flag)
{
    __shared__ float gm[160];
    int isb = flag[0];
    int g = blockIdx.x, t = threadIdx.x;
    int c = gcnt[g]; if (c < 1) c = 1;
    gm[t] = gsum[g * 128 + t] / (float)c;
    if (t < 32) {
        float a = ldf(bgp, t, isb);
        for (int d = 0; d < 6; d++) a += ldf(gx, g * 6 + d, isb) * ldf(Wgp, d * 32 + t, isb);
        gm[128 + t] = fmaxf(a, 0.f);
    }
    __syncthreads();
    float a = ldf(bgc, t, isb);
    for (int k = 0; k < 160; k++) a += gm[k] * ldf(Wgc, k * 128 + t, isb);
    if (isb) ((ushort_t*)out)[g * 128 + t] = f2bf(a);
    else     ((float*)out)[g * 128 + t] = a;
}

extern "C" void kernel_launch(void* const* d_in, const int* in_sizes, int n_in,
                              void* d_out, int out_size, void* d_ws, size_t ws_size,
                              hipStream_t stream) {
    const void* x       = d_in[0];
    const void* ea_raw  = d_in[1];
    const void* gx      = d_in[2];
    const void* W_in    = d_in[3];
    const void* b_in    = d_in[4];
    const void* W_edge  = d_in[5];
    const void* b_edge  = d_in[6];
    const void* W_gcn   = d_in[7];
    const void* b_gcn   = d_in[8];
    const void* bn_g    = d_in[9];
    const void* bn_b    = d_in[10];
    const void* bn_m    = d_in[11];
    const void* bn_v    = d_in[12];
    const void* W_gproj = d_in[13];
    const void* b_gproj = d_in[14];
    const void* W_gcomb = d_in[15];
    const void* b_gcomb = d_in[16];
    const int* row   = (const int*)d_in[17];
    const int* col   = (const int*)d_in[18];
    const int* batch = (const int*)d_in[19];

    char* ws = (char*)d_ws;
    size_t off = 0;
    int*      cnt     = (int*)(ws + off);      off += (size_t)N_NODES * 4;
    int*      cursor  = (int*)(ws + off);      off += (size_t)N_NODES * 4;
    float*    gsum    = (float*)(ws + off);    off += (size_t)NG * HD * 4;
    int*      gcnt    = (int*)(ws + off);      off += 256;
    size_t zero_bytes = off;                    // [cnt|cursor|gsum|gcnt]
    int*      flag    = (int*)(ws + off);      off += 256;
    int*      csr_off = (int*)(ws + off);      off += (size_t)N_NODES * 4;
    uint2*    csr     = (uint2*)(ws + off);    off += (size_t)CSR_CAP * 8;
    ushort_t* hbuf    = (ushort_t*)(ws + off); off += (size_t)(N_NODES + 1) * HD * 2;
    ushort_t* tbuf    = (ushort_t*)(ws + off); off += (size_t)N_NODES * HD * 2;
    float*    sc      = (float*)(ws + off);    off += (size_t)NL * HD * 4;
    float*    sh      = (float*)(ws + off);    off += (size_t)NL * HD * 4;

    hipMemsetAsync(ws, 0, zero_bytes, stream);
    hipMemsetAsync(hbuf + (size_t)N_NODES * HD, 0, HD * 2, stream);  // dummy row N
    detect_k<<<1, 256, 0, stream>>>((const uint32_t*)ea_raw, flag);
    prep_bn<<<3, 128, 0, stream>>>(bn_g, bn_b, bn_m, bn_v, b_gcn, sc, sh, flag);
    hist_k<<<N_EDGES / 256, 256, 0, stream>>>(row, cnt);
    scan_k<<<1, 1024, 0, stream>>>(cnt, csr_off);
    fill_k<<<(CSR_CAP / 2 + 255) / 256, 256, 0, stream>>>((uint4*)csr);
    scatter_k<<<N_EDGES / 256, 256, 0, stream>>>(row, col, ea_raw, csr_off, cursor,
                                                 csr, flag);
    gemm_in_k<<<N_NODES / 64, 256, 0, stream>>>(x, W_in, b_in, hbuf, flag);

    for (int l = 0; l < NL; l++) {
        aggregate_k<<<N_NODES / 4, 256, 0, stream>>>(
            (const uint32_t*)hbuf, csr_off, cnt, csr,
            W_edge, b_edge, (uint32_t*)tbuf, flag);
        gemm_layer_k<<<N_NODES / 64, 256, 0, stream>>>(
            tbuf, (const char*)W_gcn + (size_t)l * HD * HD * 4, sc + l * HD, sh + l * HD,
            hbuf, flag);
    }

    pool_k<<<N_NODES / 256, 128, 0, stream>>>(hbuf, batch, gsum, gcnt);
    final_k<<<NG, 128, 0, stream>>>(gsum, gcnt, gx, W_gproj, b_gproj,
                                    W_gcomb, b_gcomb, d_out, flag);
}

// Round 4
// 758.527 us; speedup vs baseline: 1.4794x; 1.1615x over previous
//
#include <hip/hip_runtime.h>
#include <stdint.h>

#define N_NODES 131072
#define N_EDGES 2097152
#define NG 64
#define HD 128
#define NL 3
#define EPSB 1e-5f

#define BUCKETS 256
#define BSHIFT 9               // 512 rows per bucket
#define ROWS_PB 512
#define CHUNK 8192             // edges per phase-A workgroup
#define NCHUNK (N_EDGES / CHUNK)   // 256
#define PAD_SLACK (7 * ROWS_PB)    // max pad8 slack per bucket = 3584
#define CSR_CAP (N_EDGES + BUCKETS * PAD_SLACK)

typedef unsigned short ushort_t;
typedef __bf16 bf16x8 __attribute__((ext_vector_type(8)));
typedef float f32x4 __attribute__((ext_vector_type(4)));

__device__ __forceinline__ float bf2f(uint32_t u16) {
    union { uint32_t i; float f; } c; c.i = u16 << 16; return c.f;
}
__device__ __forceinline__ float lo2f(uint32_t u) {
    union { uint32_t i; float f; } c; c.i = u << 16; return c.f;
}
__device__ __forceinline__ float hi2f(uint32_t u) {
    union { uint32_t i; float f; } c; c.i = u & 0xffff0000u; return c.f;
}
__device__ __forceinline__ ushort_t f2bf(float f) {
    union { float f; uint32_t i; } c; c.f = f;
    uint32_t u = c.i;
    uint32_t r = (u + 0x7fffu + ((u >> 16) & 1u)) >> 16;
    return (ushort_t)r;
}
// dtype-adaptive scalar load: isb=1 -> bf16 array, isb=0 -> fp32 array
__device__ __forceinline__ float ldf(const void* p, int i, int isb) {
    return isb ? bf2f(((const ushort_t*)p)[i]) : ((const float*)p)[i];
}

// ---------------- dtype sniffer on edge_attr_raw
__global__ void detect_k(const uint32_t* __restrict__ ea, int* __restrict__ flag) {
    __shared__ int sm[256];
    int t = threadIdx.x;
    int plaus = 0;
    for (int j = 0; j < 16; j++) {
        uint32_t w = ea[t * 16 + j];
        uint32_t e0 = (w >> 7) & 0xFF;
        uint32_t e1 = (w >> 23) & 0xFF;
        plaus += (e0 >= 100 && e0 <= 140) ? 1 : 0;
        plaus += (e1 >= 100 && e1 <= 140) ? 1 : 0;
    }
    sm[t] = plaus;
    __syncthreads();
    for (int o = 128; o > 0; o >>= 1) {
        if (t < o) sm[t] += sm[t + o];
        __syncthreads();
    }
    if (t == 0) flag[0] = (sm[0] * 10 >= 8192 * 9) ? 1 : 0;
}

// ---------------- BN fold
__global__ void prep_bn(const void* gamma, const void* beta,
                        const void* mean, const void* var,
                        const void* bgcn, float* sc, float* sh,
                        const int* __restrict__ flag) {
    int isb = flag[0];
    int i = blockIdx.x * 128 + threadIdx.x;
    if (i < NL * HD) {
        float g = ldf(gamma, i, isb), b = ldf(beta, i, isb);
        float m = ldf(mean, i, isb), v = ldf(var, i, isb), bb = ldf(bgcn, i, isb);
        float s = g / sqrtf(v + EPSB);
        sc[i] = s;
        sh[i] = (bb - m) * s + b;
    }
}

// ---------------- Phase A: per-chunk bucket partition, XCD-exclusive writes
// entry.x = (local_row<<17) | col, entry.y = packed bf16 edge attrs
__global__ __launch_bounds__(256) void bucketA_k(
    const int* __restrict__ row, const int* __restrict__ col,
    const void* __restrict__ ea_raw,
    uint2* __restrict__ staged, uint32_t* __restrict__ cntmat,
    uint32_t* __restrict__ offmat, const int* __restrict__ flag)
{
    __shared__ int hist[256], offs[256], offs_ex[256], cur[256];
    int isb = flag[0];
    int t = threadIdx.x;
    int base = blockIdx.x * CHUNK;
    hist[t] = 0;
    __syncthreads();
#pragma unroll 4
    for (int j = 0; j < 32; j++) {
        int r = row[base + j * 256 + t];
        atomicAdd(&hist[r >> BSHIFT], 1);
    }
    __syncthreads();
    int v = hist[t];
    offs[t] = v;
    __syncthreads();
    for (int o = 1; o < 256; o <<= 1) {
        int u = (t >= o) ? offs[t - o] : 0;
        __syncthreads();
        offs[t] += u;
        __syncthreads();
    }
    offs_ex[t] = offs[t] - v;
    cur[t] = 0;
    cntmat[blockIdx.x * 256 + t] = (uint32_t)v;       // [slice][bucket]
    offmat[blockIdx.x * 256 + t] = (uint32_t)(offs[t] - v);
    __syncthreads();
    uint2* slice = staged + (size_t)blockIdx.x * CHUNK;
    for (int j = 0; j < 32; j++) {
        int e = base + j * 256 + t;
        int r = row[e];
        int b = r >> BSHIFT;
        uint32_t packed;
        if (isb) {
            packed = ((const uint32_t*)ea_raw)[e];
        } else {
            const float* f = (const float*)ea_raw + (size_t)e * 2;
            packed = (uint32_t)f2bf(f[0]) | ((uint32_t)f2bf(f[1]) << 16);
        }
        int pos = offs_ex[b] + atomicAdd(&cur[b], 1);
        slice[pos] = make_uint2((uint32_t)(((r & (ROWS_PB - 1)) << 17) | col[e]), packed);
    }
}

// ---------------- per-bucket totals
__global__ __launch_bounds__(256) void bucketsum_k(const uint32_t* __restrict__ cntmat,
                                                   uint32_t* __restrict__ btot) {
    __shared__ int sm[256];
    int b = blockIdx.x, t = threadIdx.x;
    sm[t] = (int)cntmat[t * 256 + b];
    __syncthreads();
    for (int o = 128; o > 0; o >>= 1) {
        if (t < o) sm[t] += sm[t + o];
        __syncthreads();
    }
    if (t == 0) btot[b] = (uint32_t)sm[0];
}

// ---------------- bucket bases (over-allocated by PAD_SLACK, gaps never read)
__global__ __launch_bounds__(256) void scan2_k(const uint32_t* __restrict__ btot,
                                               uint32_t* __restrict__ bbase) {
    __shared__ int sm[256];
    int t = threadIdx.x;
    int v = (int)btot[t] + PAD_SLACK;
    sm[t] = v;
    __syncthreads();
    for (int o = 1; o < 256; o <<= 1) {
        int u = (t >= o) ? sm[t - o] : 0;
        __syncthreads();
        sm[t] += u;
        __syncthreads();
    }
    bbase[t] = (uint32_t)(sm[t] - v);
}

// ---------------- Phase B: one bucket per WG; build padded CSR span exclusively
__global__ __launch_bounds__(512) void buildB_k(
    const uint2* __restrict__ staged, const uint32_t* __restrict__ cntmat,
    const uint32_t* __restrict__ offmat, const uint32_t* __restrict__ bbase,
    uint2* __restrict__ csr, int* __restrict__ csr_off, int* __restrict__ deg)
{
    __shared__ int runoff[257];
    __shared__ int runstart[256];
    __shared__ int hist2[512];
    __shared__ int po[512];
    __shared__ int cur2[512];
    int b = blockIdx.x, t = threadIdx.x;

    // exclusive scan of run lengths over 256 slices
    int myc = 0;
    if (t < 256) {
        myc = (int)cntmat[t * 256 + b];
        runstart[t] = t * CHUNK + (int)offmat[t * 256 + b];
        runoff[t] = myc;
    }
    __syncthreads();
    for (int o = 1; o < 256; o <<= 1) {
        int u = 0;
        if (t < 256 && t >= o) u = runoff[t - o];
        __syncthreads();
        if (t < 256) runoff[t] += u;
        __syncthreads();
    }
    if (t < 256) {
        int incl = runoff[t];
        runoff[t] = incl - myc;          // exclusive
        if (t == 255) runoff[256] = incl; // total
    }
    hist2[t] = 0;
    cur2[t] = 0;
    __syncthreads();
    int T = runoff[256];

    // pass 1: per-row histogram
    for (int i = t; i < T; i += 512) {
        int lo = 0, hi = 255;
        while (lo < hi) { int mid = (lo + hi + 1) >> 1; if (runoff[mid] <= i) lo = mid; else hi = mid - 1; }
        uint32_t x = staged[runstart[lo] + (i - runoff[lo])].x;
        atomicAdd(&hist2[x >> 17], 1);
    }
    __syncthreads();

    // padded exclusive scan over 512 rows
    int pv = (hist2[t] + 7) & ~7;
    po[t] = pv;
    __syncthreads();
    for (int o = 1; o < 512; o <<= 1) {
        int u = (t >= o) ? po[t - o] : 0;
        __syncthreads();
        po[t] += u;
        __syncthreads();
    }
    po[t] -= pv;                          // exclusive padded offset within bucket
    __syncthreads();

    int gbase = (int)bbase[b];
    csr_off[b * ROWS_PB + t] = gbase + po[t];
    deg[b * ROWS_PB + t] = hist2[t];

    // pass 2: scatter into exclusive bucket span
    for (int i = t; i < T; i += 512) {
        int lo = 0, hi = 255;
        while (lo < hi) { int mid = (lo + hi + 1) >> 1; if (runoff[mid] <= i) lo = mid; else hi = mid - 1; }
        uint2 en = staged[runstart[lo] + (i - runoff[lo])];
        int r = en.x >> 17;
        int pos = po[r] + atomicAdd(&cur2[r], 1);
        csr[gbase + pos] = make_uint2(en.x & 0x1FFFFu, en.y);
    }
    __syncthreads();
    // sentinels in pad slots
    int d = hist2[t], p = (d + 7) & ~7;
    for (int k = d; k < p; k++) csr[gbase + po[t] + k] = make_uint2(N_NODES, 0u);
}

// ---------------- aggregate: one wave per node, 8 gathers in flight
__global__ __launch_bounds__(256) void aggregate_k(
    const uint32_t* __restrict__ h32,      // [N+1, 64] u32 (bf16x2), row N zeroed
    const int* __restrict__ csr_off, const int* __restrict__ cnt,
    const uint2* __restrict__ csr,
    const void* __restrict__ Wedge,        // [2,128]
    const void* __restrict__ bedge,        // [128]
    uint32_t* __restrict__ t32,            // out [N,64] u32
    const int* __restrict__ flag)
{
    int isb = flag[0];
    int lane = threadIdx.x & 63;
    int node = __builtin_amdgcn_readfirstlane(blockIdx.x * 4 + (threadIdx.x >> 6));

    float w0x = ldf(Wedge, 2 * lane, isb),       w0y = ldf(Wedge, 2 * lane + 1, isb);
    float w1x = ldf(Wedge, 128 + 2 * lane, isb), w1y = ldf(Wedge, 128 + 2 * lane + 1, isb);
    float bex = ldf(bedge, 2 * lane, isb),       bey = ldf(bedge, 2 * lane + 1, isb);

    int start = csr_off[node];          // multiple of 8 entries (64B aligned)
    int deg = cnt[node];
    int iters = (deg + 7) >> 3;
    const uint4* seg = (const uint4*)(csr + start);   // 2 edges per uint4

    float ax = 0.f, ay = 0.f;
    for (int it = 0; it < iters; it++) {
        uint4 q0 = seg[it * 4 + 0];
        uint4 q1 = seg[it * 4 + 1];
        uint4 q2 = seg[it * 4 + 2];
        uint4 q3 = seg[it * 4 + 3];
        uint32_t cols[8] = {q0.x, q0.z, q1.x, q1.z, q2.x, q2.z, q3.x, q3.z};
        uint32_t eav[8]  = {q0.y, q0.w, q1.y, q1.w, q2.y, q2.w, q3.y, q3.w};
        uint32_t hv[8];
#pragma unroll
        for (int j = 0; j < 8; j++) hv[j] = h32[cols[j] * 64 + lane];
#pragma unroll
        for (int j = 0; j < 8; j++) {
            float a0 = bf2f(eav[j] & 0xffffu);
            float a1 = bf2f(eav[j] >> 16);
            float eax = a0 * w0x + a1 * w1x + bex;
            float eay = a0 * w0y + a1 * w1y + bey;
            ax += lo2f(hv[j]) * eax;
            ay += hi2f(hv[j]) * eay;
        }
    }
    float inv = 1.0f / (float)(deg > 0 ? deg : 1);
    uint32_t hn = h32[node * 64 + lane];
    float tx = lo2f(hn) + ax * inv;
    float ty = hi2f(hn) + ay * inv;
    t32[node * 64 + lane] = (uint32_t)f2bf(tx) | ((uint32_t)f2bf(ty) << 16);
}

// ---------------- GEMM: h0 = x @ W_in + b_in   ([N,64]x[64,128]) -> internal bf16
__global__ __launch_bounds__(256) void gemm_in_k(
    const void* __restrict__ X, const void* __restrict__ W,
    const void* __restrict__ bin, ushort_t* __restrict__ Hout,
    const int* __restrict__ flag)
{
    __shared__ ushort_t WT[128 * 72];
    int isb = flag[0];
    int tid = threadIdx.x;
    for (int idx = tid; idx < 64 * 128; idx += 256) {
        int k = idx >> 7, n = idx & 127;
        WT[n * 72 + k] = f2bf(ldf(W, idx, isb));
    }
    __syncthreads();
    int wave = tid >> 6, lane = tid & 63;
    int quad = lane >> 4, l16 = lane & 15;
    int row = blockIdx.x * 64 + wave * 16 + l16;

    f32x4 acc[8];
#pragma unroll
    for (int c = 0; c < 8; c++) acc[c] = (f32x4){0.f, 0.f, 0.f, 0.f};

#pragma unroll
    for (int kk = 0; kk < 2; kk++) {
        int aoff = row * 64 + kk * 32 + quad * 8;
        union { bf16x8 v; ushort_t s[8]; } a;
        if (isb) {
            a.v = *(const bf16x8*)((const ushort_t*)X + aoff);
        } else {
            const float* xf = (const float*)X + aoff;
            f32x4 p0 = *(const f32x4*)xf;
            f32x4 p1 = *(const f32x4*)(xf + 4);
#pragma unroll
            for (int j = 0; j < 4; j++) { a.s[j] = f2bf(p0[j]); a.s[4 + j] = f2bf(p1[j]); }
        }
#pragma unroll
        for (int c = 0; c < 8; c++) {
            bf16x8 b = *(const bf16x8*)(&WT[(c * 16 + l16) * 72 + kk * 32 + quad * 8]);
            acc[c] = __builtin_amdgcn_mfma_f32_16x16x32_bf16(a.v, b, acc[c], 0, 0, 0);
        }
    }
    int rbase = blockIdx.x * 64 + wave * 16 + quad * 4;
#pragma unroll
    for (int c = 0; c < 8; c++) {
        int gcol = c * 16 + l16;
        float bb = ldf(bin, gcol, isb);
#pragma unroll
        for (int r = 0; r < 4; r++) {
            Hout[(rbase + r) * 128 + gcol] = f2bf(acc[c][r] + bb);
        }
    }
}

// ---------------- GEMM + BN + ReLU: h = relu((t @ W)*sc + sh)
__global__ __launch_bounds__(256) void gemm_layer_k(
    const ushort_t* __restrict__ T, const void* __restrict__ W,
    const float* __restrict__ sc, const float* __restrict__ sh,
    ushort_t* __restrict__ Hout, const int* __restrict__ flag)
{
    __shared__ ushort_t WT[128 * 136];
    int isb = flag[0];
    int tid = threadIdx.x;
    for (int idx = tid; idx < 128 * 128; idx += 256) {
        int k = idx >> 7, n = idx & 127;
        WT[n * 136 + k] = f2bf(ldf(W, idx, isb));
    }
    __syncthreads();
    int wave = tid >> 6, lane = tid & 63;
    int quad = lane >> 4, l16 = lane & 15;
    int row = blockIdx.x * 64 + wave * 16 + l16;

    f32x4 acc[8];
#pragma unroll
    for (int c = 0; c < 8; c++) acc[c] = (f32x4){0.f, 0.f, 0.f, 0.f};

#pragma unroll
    for (int kk = 0; kk < 4; kk++) {
        bf16x8 a = *(const bf16x8*)(T + row * 128 + kk * 32 + quad * 8);
#pragma unroll
        for (int c = 0; c < 8; c++) {
            bf16x8 b = *(const bf16x8*)(&WT[(c * 16 + l16) * 136 + kk * 32 + quad * 8]);
            acc[c] = __builtin_amdgcn_mfma_f32_16x16x32_bf16(a, b, acc[c], 0, 0, 0);
        }
    }
    int rbase = blockIdx.x * 64 + wave * 16 + quad * 4;
#pragma unroll
    for (int c = 0; c < 8; c++) {
        int gcol = c * 16 + l16;
        float s = sc[gcol], o = sh[gcol];
#pragma unroll
        for (int r = 0; r < 4; r++) {
            float v = acc[c][r] * s + o;
            v = fmaxf(v, 0.f);
            Hout[(rbase + r) * 128 + gcol] = f2bf(v);
        }
    }
}

// ---------------- pool
__global__ __launch_bounds__(128) void pool_k(
    const ushort_t* __restrict__ Hf, const int* __restrict__ batch,
    float* __restrict__ gsum, int* __restrict__ gcnt)
{
    int t = threadIdx.x;
    int n0 = blockIdx.x * 256;
    int n1 = n0 + 256;
    int cur = batch[n0];
    float s = 0.f; int c = 0;
    for (int n = n0; n < n1; n++) {
        int g = batch[n];
        if (g != cur) {
            atomicAdd(&gsum[cur * 128 + t], s);
            if (t == 0) atomicAdd(&gcnt[cur], c);
            s = 0.f; c = 0; cur = g;
        }
        s += bf2f(Hf[n * 128 + t]);
        c++;
    }
    atomicAdd(&gsum[cur * 128 + t], s);
    if (t == 0) atomicAdd(&gcnt[cur], c);
}

// ---------------- final
__global__ __launch_bounds__(128) void final_k(
    const float* __restrict__ gsum, const int* __restrict__ gcnt,
    const void* __restrict__ gx, const void* __restrict__ Wgp,
    const void* __restrict__ bgp, const void* __restrict__ Wgc,
    const void* __restrict__ bgc, void* __restrict__ out,
    const int* __restrict__ flag)
{
    __shared__ float gm[160];
    int isb = flag[0];
    int g = blockIdx.x, t = threadIdx.x;
    int c = gcnt[g]; if (c < 1) c = 1;
    gm[t] = gsum[g * 128 + t] / (float)c;
    if (t < 32) {
        float a = ldf(bgp, t, isb);
        for (int d = 0; d < 6; d++) a += ldf(gx, g * 6 + d, isb) * ldf(Wgp, d * 32 + t, isb);
        gm[128 + t] = fmaxf(a, 0.f);
    }
    __syncthreads();
    float a = ldf(bgc, t, isb);
    for (int k = 0; k < 160; k++) a += gm[k] * ldf(Wgc, k * 128 + t, isb);
    if (isb) ((ushort_t*)out)[g * 128 + t] = f2bf(a);
    else     ((float*)out)[g * 128 + t] = a;
}

extern "C" void kernel_launch(void* const* d_in, const int* in_sizes, int n_in,
                              void* d_out, int out_size, void* d_ws, size_t ws_size,
                              hipStream_t stream) {
    const void* x       = d_in[0];
    const void* ea_raw  = d_in[1];
    const void* gx      = d_in[2];
    const void* W_in    = d_in[3];
    const void* b_in    = d_in[4];
    const void* W_edge  = d_in[5];
    const void* b_edge  = d_in[6];
    const void* W_gcn   = d_in[7];
    const void* b_gcn   = d_in[8];
    const void* bn_g    = d_in[9];
    const void* bn_b    = d_in[10];
    const void* bn_m    = d_in[11];
    const void* bn_v    = d_in[12];
    const void* W_gproj = d_in[13];
    const void* b_gproj = d_in[14];
    const void* W_gcomb = d_in[15];
    const void* b_gcomb = d_in[16];
    const int* row   = (const int*)d_in[17];
    const int* col   = (const int*)d_in[18];
    const int* batch = (const int*)d_in[19];

    char* ws = (char*)d_ws;
    size_t off = 0;
    float*    gsum    = (float*)(ws + off);    off += (size_t)NG * HD * 4;
    int*      gcnt    = (int*)(ws + off);      off += 256;
    size_t zero_bytes = off;                    // [gsum|gcnt]
    int*      flag    = (int*)(ws + off);      off += 256;
    uint32_t* cntmat  = (uint32_t*)(ws + off); off += 256 * 256 * 4;
    uint32_t* offmat  = (uint32_t*)(ws + off); off += 256 * 256 * 4;
    uint32_t* btot    = (uint32_t*)(ws + off); off += 1024;
    uint32_t* bbase   = (uint32_t*)(ws + off); off += 1024;
    int*      csr_off = (int*)(ws + off);      off += (size_t)N_NODES * 4;
    int*      deg     = (int*)(ws + off);      off += (size_t)N_NODES * 4;
    uint2*    csr     = (uint2*)(ws + off);    off += (size_t)CSR_CAP * 8;
    ushort_t* hbuf    = (ushort_t*)(ws + off); off += (size_t)(N_NODES + 1) * HD * 2;
    ushort_t* tbuf    = (ushort_t*)(ws + off); off += (size_t)N_NODES * HD * 2;
    float*    sc      = (float*)(ws + off);    off += (size_t)NL * HD * 4;
    float*    sh      = (float*)(ws + off);    off += (size_t)NL * HD * 4;
    uint2*    staged  = (uint2*)tbuf;  // overlay: staged dead before aggregate writes tbuf

    hipMemsetAsync(ws, 0, zero_bytes, stream);
    hipMemsetAsync(hbuf + (size_t)N_NODES * HD, 0, HD * 2, stream);  // dummy row N
    detect_k<<<1, 256, 0, stream>>>((const uint32_t*)ea_raw, flag);
    prep_bn<<<3, 128, 0, stream>>>(bn_g, bn_b, bn_m, bn_v, b_gcn, sc, sh, flag);

    bucketA_k<<<NCHUNK, 256, 0, stream>>>(row, col, ea_raw, staged, cntmat, offmat, flag);
    bucketsum_k<<<BUCKETS, 256, 0, stream>>>(cntmat, btot);
    scan2_k<<<1, 256, 0, stream>>>(btot, bbase);
    buildB_k<<<BUCKETS, 512, 0, stream>>>(staged, cntmat, offmat, bbase, csr, csr_off, deg);

    gemm_in_k<<<N_NODES / 64, 256, 0, stream>>>(x, W_in, b_in, hbuf, flag);

    for (int l = 0; l < NL; l++) {
        aggregate_k<<<N_NODES / 4, 256, 0, stream>>>(
            (const uint32_t*)hbuf, csr_off, deg, csr,
            W_edge, b_edge, (uint32_t*)tbuf, flag);
        gemm_layer_k<<<N_NODES / 64, 256, 0, stream>>>(
            tbuf, (const char*)W_gcn + (size_t)l * HD * HD * 4, sc + l * HD, sh + l * HD,
            hbuf, flag);
    }

    pool_k<<<N_NODES / 256, 128, 0, stream>>>(hbuf, batch, gsum, gcnt);
    final_k<<<NG, 128, 0, stream>>>(gsum, gcnt, gx, W_gproj, b_gproj,
                                    W_gcomb, b_gcomb, d_out, flag);
}

// Round 6
// 697.762 us; speedup vs baseline: 1.6082x; 1.0871x over previous
//
#include <hip/hip_runtime.h>
#include <stdint.h>

#define N_NODES 131072
#define N_EDGES 2097152
#define NG 64
#define HD 128
#define NL 3
#define EPSB 1e-5f

#define BUCKETS 256
#define BSHIFT 9               // 512 rows per bucket
#define ROWS_PB 512
#define CHUNK 8192             // edges per phase-A workgroup
#define NCHUNK (N_EDGES / CHUNK)   // 256
#define PAD_SLACK (7 * ROWS_PB)    // max pad8 slack per bucket = 3584
#define CSR_CAP (N_EDGES + BUCKETS * (PAD_SLACK + 8))
#define TPAD 68                // dword stride of per-wave LDS tile (16B aligned, 2-way banks)

typedef unsigned short ushort_t;
typedef __bf16 bf16x8 __attribute__((ext_vector_type(8)));
typedef float f32x4 __attribute__((ext_vector_type(4)));

__device__ __forceinline__ float bf2f(uint32_t u16) {
    union { uint32_t i; float f; } c; c.i = u16 << 16; return c.f;
}
__device__ __forceinline__ float lo2f(uint32_t u) {
    union { uint32_t i; float f; } c; c.i = u << 16; return c.f;
}
__device__ __forceinline__ float hi2f(uint32_t u) {
    union { uint32_t i; float f; } c; c.i = u & 0xffff0000u; return c.f;
}
__device__ __forceinline__ ushort_t f2bf(float f) {
    union { float f; uint32_t i; } c; c.f = f;
    uint32_t u = c.i;
    uint32_t r = (u + 0x7fffu + ((u >> 16) & 1u)) >> 16;
    return (ushort_t)r;
}
// dtype-adaptive scalar load: isb=1 -> bf16 array, isb=0 -> fp32 array
__device__ __forceinline__ float ldf(const void* p, int i, int isb) {
    return isb ? bf2f(((const ushort_t*)p)[i]) : ((const float*)p)[i];
}

// ---------------- dtype sniffer on edge_attr_raw
__global__ void detect_k(const uint32_t* __restrict__ ea, int* __restrict__ flag) {
    __shared__ int sm[256];
    int t = threadIdx.x;
    int plaus = 0;
    for (int j = 0; j < 16; j++) {
        uint32_t w = ea[t * 16 + j];
        uint32_t e0 = (w >> 7) & 0xFF;
        uint32_t e1 = (w >> 23) & 0xFF;
        plaus += (e0 >= 100 && e0 <= 140) ? 1 : 0;
        plaus += (e1 >= 100 && e1 <= 140) ? 1 : 0;
    }
    sm[t] = plaus;
    __syncthreads();
    for (int o = 128; o > 0; o >>= 1) {
        if (t < o) sm[t] += sm[t + o];
        __syncthreads();
    }
    if (t == 0) flag[0] = (sm[0] * 10 >= 8192 * 9) ? 1 : 0;
}

// ---------------- BN fold
__global__ void prep_bn(const void* gamma, const void* beta,
                        const void* mean, const void* var,
                        const void* bgcn, float* sc, float* sh,
                        const int* __restrict__ flag) {
    int isb = flag[0];
    int i = blockIdx.x * 128 + threadIdx.x;
    if (i < NL * HD) {
        float g = ldf(gamma, i, isb), b = ldf(beta, i, isb);
        float m = ldf(mean, i, isb), v = ldf(var, i, isb), bb = ldf(bgcn, i, isb);
        float s = g / sqrtf(v + EPSB);
        sc[i] = s;
        sh[i] = (bb - m) * s + b;
    }
}

// ---------------- pre-transpose W_gcn: WTg[l][n][k] = W[l][k][n], as bf16
__global__ void transpose_k(const void* __restrict__ W, ushort_t* __restrict__ WTg,
                            const int* __restrict__ flag) {
    int isb = flag[0];
    int idx = blockIdx.x * 256 + threadIdx.x;
    if (idx < NL * HD * HD) {
        int l = idx >> 14;
        int rem = idx & 16383;
        int k = rem >> 7, n = rem & 127;
        WTg[l * 16384 + n * 128 + k] = f2bf(ldf(W, idx, isb));
    }
}

// ---------------- Phase A: per-chunk bucket partition, XCD-exclusive writes
__global__ __launch_bounds__(256) void bucketA_k(
    const int* __restrict__ row, const int* __restrict__ col,
    const void* __restrict__ ea_raw,
    uint2* __restrict__ staged, uint32_t* __restrict__ cntmat,
    uint32_t* __restrict__ offmat, const int* __restrict__ flag)
{
    __shared__ int hist[256], offs[256], offs_ex[256], cur[256];
    int isb = flag[0];
    int t = threadIdx.x;
    int base = blockIdx.x * CHUNK;
    hist[t] = 0;
    __syncthreads();
#pragma unroll 4
    for (int j = 0; j < 32; j++) {
        int r = row[base + j * 256 + t];
        atomicAdd(&hist[r >> BSHIFT], 1);
    }
    __syncthreads();
    int v = hist[t];
    offs[t] = v;
    __syncthreads();
    for (int o = 1; o < 256; o <<= 1) {
        int u = (t >= o) ? offs[t - o] : 0;
        __syncthreads();
        offs[t] += u;
        __syncthreads();
    }
    offs_ex[t] = offs[t] - v;
    cur[t] = 0;
    cntmat[blockIdx.x * 256 + t] = (uint32_t)v;
    offmat[blockIdx.x * 256 + t] = (uint32_t)(offs[t] - v);
    __syncthreads();
    uint2* slice = staged + (size_t)blockIdx.x * CHUNK;
    for (int j = 0; j < 32; j++) {
        int e = base + j * 256 + t;
        int r = row[e];
        int b = r >> BSHIFT;
        uint32_t packed;
        if (isb) {
            packed = ((const uint32_t*)ea_raw)[e];
        } else {
            const float* f = (const float*)ea_raw + (size_t)e * 2;
            packed = (uint32_t)f2bf(f[0]) | ((uint32_t)f2bf(f[1]) << 16);
        }
        int pos = offs_ex[b] + atomicAdd(&cur[b], 1);
        slice[pos] = make_uint2((uint32_t)(((r & (ROWS_PB - 1)) << 17) | col[e]), packed);
    }
}

// ---------------- per-bucket totals
__global__ __launch_bounds__(256) void bucketsum_k(const uint32_t* __restrict__ cntmat,
                                                   uint32_t* __restrict__ btot) {
    __shared__ int sm[256];
    int b = blockIdx.x, t = threadIdx.x;
    sm[t] = (int)cntmat[t * 256 + b];
    __syncthreads();
    for (int o = 128; o > 0; o >>= 1) {
        if (t < o) sm[t] += sm[t + o];
        __syncthreads();
    }
    if (t == 0) btot[b] = (uint32_t)sm[0];
}

// ---------------- bucket bases. Capacity rounded to multiple of 8 so every
// bbase (hence every csr_off) is 8-entry aligned -> (start>>1) in the fused
// kernel is exact and uint4 reads are 16B-aligned.
__global__ __launch_bounds__(256) void scan2_k(const uint32_t* __restrict__ btot,
                                               uint32_t* __restrict__ bbase) {
    __shared__ int sm[256];
    int t = threadIdx.x;
    int v = ((int)btot[t] + PAD_SLACK + 7) & ~7;
    sm[t] = v;
    __syncthreads();
    for (int o = 1; o < 256; o <<= 1) {
        int u = (t >= o) ? sm[t - o] : 0;
        __syncthreads();
        sm[t] += u;
        __syncthreads();
    }
    bbase[t] = (uint32_t)(sm[t] - v);
}

// ---------------- Phase B: one bucket per WG; build padded CSR span exclusively
__global__ __launch_bounds__(512) void buildB_k(
    const uint2* __restrict__ staged, const uint32_t* __restrict__ cntmat,
    const uint32_t* __restrict__ offmat, const uint32_t* __restrict__ bbase,
    uint2* __restrict__ csr, int* __restrict__ csr_off, int* __restrict__ deg)
{
    __shared__ int runoff[257];
    __shared__ int runstart[256];
    __shared__ int hist2[512];
    __shared__ int po[512];
    __shared__ int cur2[512];
    int b = blockIdx.x, t = threadIdx.x;

    int myc = 0;
    if (t < 256) {
        myc = (int)cntmat[t * 256 + b];
        runstart[t] = t * CHUNK + (int)offmat[t * 256 + b];
        runoff[t] = myc;
    }
    __syncthreads();
    for (int o = 1; o < 256; o <<= 1) {
        int u = 0;
        if (t < 256 && t >= o) u = runoff[t - o];
        __syncthreads();
        if (t < 256) runoff[t] += u;
        __syncthreads();
    }
    if (t < 256) {
        int incl = runoff[t];
        runoff[t] = incl - myc;
        if (t == 255) runoff[256] = incl;
    }
    hist2[t] = 0;
    cur2[t] = 0;
    __syncthreads();
    int T = runoff[256];

    for (int i = t; i < T; i += 512) {
        int lo = 0, hi = 255;
        while (lo < hi) { int mid = (lo + hi + 1) >> 1; if (runoff[mid] <= i) lo = mid; else hi = mid - 1; }
        uint32_t x = staged[runstart[lo] + (i - runoff[lo])].x;
        atomicAdd(&hist2[x >> 17], 1);
    }
    __syncthreads();

    int pv = (hist2[t] + 7) & ~7;
    po[t] = pv;
    __syncthreads();
    for (int o = 1; o < 512; o <<= 1) {
        int u = (t >= o) ? po[t - o] : 0;
        __syncthreads();
        po[t] += u;
        __syncthreads();
    }
    po[t] -= pv;
    __syncthreads();

    int gbase = (int)bbase[b];
    csr_off[b * ROWS_PB + t] = gbase + po[t];
    deg[b * ROWS_PB + t] = hist2[t];

    for (int i = t; i < T; i += 512) {
        int lo = 0, hi = 255;
        while (lo < hi) { int mid = (lo + hi + 1) >> 1; if (runoff[mid] <= i) lo = mid; else hi = mid - 1; }
        uint2 en = staged[runstart[lo] + (i - runoff[lo])];
        int r = en.x >> 17;
        int pos = po[r] + atomicAdd(&cur2[r], 1);
        csr[gbase + pos] = make_uint2(en.x & 0x1FFFFu, en.y);
    }
    __syncthreads();
    int d = hist2[t], p = (d + 7) & ~7;
    for (int k = d; k < p; k++) csr[gbase + po[t] + k] = make_uint2(N_NODES, 0u);
}

// ---------------- fused layer: aggregate 64 nodes/block + GEMM + BN + ReLU
// wave w handles nodes [blk*64 + w*16, +16): contiguous padded CSR stream.
__global__ __launch_bounds__(256) void layer_fused_k(
    const uint32_t* __restrict__ h32,      // [N+1,64] u32 (bf16x2), row N zeroed
    const int* __restrict__ csr_off, const int* __restrict__ degv,
    const uint2* __restrict__ csr,
    const void* __restrict__ Wedge, const void* __restrict__ bedge,
    const ushort_t* __restrict__ WTg,      // [128][128] bf16, WT[n][k]
    const float* __restrict__ sc, const float* __restrict__ sh,
    ushort_t* __restrict__ Hout,           // [N+1][128] bf16
    const int* __restrict__ flag)
{
    __shared__ uint32_t tile[4][16 * TPAD];
    int isb = flag[0];
    int tid = threadIdx.x;
    int wave = tid >> 6, lane = tid & 63;
    int quad = lane >> 4, l16 = lane & 15;
    int nodebase = __builtin_amdgcn_readfirstlane(blockIdx.x * 64 + wave * 16);

    float w0x = ldf(Wedge, 2 * lane, isb),       w0y = ldf(Wedge, 2 * lane + 1, isb);
    float w1x = ldf(Wedge, 128 + 2 * lane, isb), w1y = ldf(Wedge, 128 + 2 * lane + 1, isb);
    float bex = ldf(bedge, 2 * lane, isb),       bey = ldf(bedge, 2 * lane + 1, isb);

    uint32_t* mytile = &tile[wave][0];

    int start = csr_off[nodebase];         // multiple of 8 (aligned bucket bases)
    int dlast = degv[nodebase + 15];
    int gtotal = ((csr_off[nodebase + 15] + ((dlast + 7) & ~7)) - start) >> 3;

    int node = nodebase;
    int dg = degv[node];
    int rem = (dg + 7) >> 3;
    // leading zero-degree nodes (rare): t = h
    while (rem == 0 && node < nodebase + 16) {
        uint32_t hn = h32[node * 64 + lane];
        mytile[(node - nodebase) * TPAD + lane] = hn;  // already bf16 pair
        node++;
        if (node < nodebase + 16) { dg = degv[node]; rem = (dg + 7) >> 3; }
    }

    float ax = 0.f, ay = 0.f;
    const uint4* gp = (const uint4*)csr + (start >> 1);
    for (int g = 0; g < gtotal; g++) {
        uint4 q0 = gp[0], q1 = gp[1], q2 = gp[2], q3 = gp[3];
        gp += 4;
        uint32_t h0 = h32[q0.x * 64 + lane];
        uint32_t h1 = h32[q0.z * 64 + lane];
        uint32_t h2 = h32[q1.x * 64 + lane];
        uint32_t h3 = h32[q1.z * 64 + lane];
        uint32_t h4 = h32[q2.x * 64 + lane];
        uint32_t h5 = h32[q2.z * 64 + lane];
        uint32_t h6 = h32[q3.x * 64 + lane];
        uint32_t h7 = h32[q3.z * 64 + lane];

        float a0, a1, ex, ey;
        a0 = bf2f(q0.y & 0xffffu); a1 = bf2f(q0.y >> 16);
        ex = fmaf(a1, w1x, fmaf(a0, w0x, bex)); ey = fmaf(a1, w1y, fmaf(a0, w0y, bey));
        ax = fmaf(lo2f(h0), ex, ax); ay = fmaf(hi2f(h0), ey, ay);
        a0 = bf2f(q0.w & 0xffffu); a1 = bf2f(q0.w >> 16);
        ex = fmaf(a1, w1x, fmaf(a0, w0x, bex)); ey = fmaf(a1, w1y, fmaf(a0, w0y, bey));
        ax = fmaf(lo2f(h1), ex, ax); ay = fmaf(hi2f(h1), ey, ay);
        a0 = bf2f(q1.y & 0xffffu); a1 = bf2f(q1.y >> 16);
        ex = fmaf(a1, w1x, fmaf(a0, w0x, bex)); ey = fmaf(a1, w1y, fmaf(a0, w0y, bey));
        ax = fmaf(lo2f(h2), ex, ax); ay = fmaf(hi2f(h2), ey, ay);
        a0 = bf2f(q1.w & 0xffffu); a1 = bf2f(q1.w >> 16);
        ex = fmaf(a1, w1x, fmaf(a0, w0x, bex)); ey = fmaf(a1, w1y, fmaf(a0, w0y, bey));
        ax = fmaf(lo2f(h3), ex, ax); ay = fmaf(hi2f(h3), ey, ay);
        a0 = bf2f(q2.y & 0xffffu); a1 = bf2f(q2.y >> 16);
        ex = fmaf(a1, w1x, fmaf(a0, w0x, bex)); ey = fmaf(a1, w1y, fmaf(a0, w0y, bey));
        ax = fmaf(lo2f(h4), ex, ax); ay = fmaf(hi2f(h4), ey, ay);
        a0 = bf2f(q2.w & 0xffffu); a1 = bf2f(q2.w >> 16);
        ex = fmaf(a1, w1x, fmaf(a0, w0x, bex)); ey = fmaf(a1, w1y, fmaf(a0, w0y, bey));
        ax = fmaf(lo2f(h5), ex, ax); ay = fmaf(hi2f(h5), ey, ay);
        a0 = bf2f(q3.y & 0xffffu); a1 = bf2f(q3.y >> 16);
        ex = fmaf(a1, w1x, fmaf(a0, w0x, bex)); ey = fmaf(a1, w1y, fmaf(a0, w0y, bey));
        ax = fmaf(lo2f(h6), ex, ax); ay = fmaf(hi2f(h6), ey, ay);
        a0 = bf2f(q3.w & 0xffffu); a1 = bf2f(q3.w >> 16);
        ex = fmaf(a1, w1x, fmaf(a0, w0x, bex)); ey = fmaf(a1, w1y, fmaf(a0, w0y, bey));
        ax = fmaf(lo2f(h7), ex, ax); ay = fmaf(hi2f(h7), ey, ay);

        rem--;
        while (rem == 0) {
            float inv = 1.0f / (float)(dg > 0 ? dg : 1);
            uint32_t hn = h32[node * 64 + lane];
            float tx = lo2f(hn) + ax * inv;
            float ty = hi2f(hn) + ay * inv;
            mytile[(node - nodebase) * TPAD + lane] =
                (uint32_t)f2bf(tx) | ((uint32_t)f2bf(ty) << 16);
            ax = 0.f; ay = 0.f;
            node++;
            if (node == nodebase + 16) break;
            dg = degv[node];
            rem = (dg + 7) >> 3;
        }
    }
    // trailing all-zero-degree safeguard
    while (node < nodebase + 16) {
        uint32_t hn = h32[node * 64 + lane];
        mytile[(node - nodebase) * TPAD + lane] = hn;
        node++;
    }
    __syncthreads();

    f32x4 acc[8];
#pragma unroll
    for (int c = 0; c < 8; c++) acc[c] = (f32x4){0.f, 0.f, 0.f, 0.f};

#pragma unroll
    for (int kk = 0; kk < 4; kk++) {
        bf16x8 a = *(const bf16x8*)(mytile + l16 * TPAD + kk * 16 + quad * 4);
#pragma unroll
        for (int c = 0; c < 8; c++) {
            bf16x8 b = *(const bf16x8*)(WTg + (c * 16 + l16) * 128 + kk * 32 + quad * 8);
            acc[c] = __builtin_amdgcn_mfma_f32_16x16x32_bf16(a, b, acc[c], 0, 0, 0);
        }
    }
#pragma unroll
    for (int c = 0; c < 8; c++) {
        int gcol = c * 16 + l16;
        float s = sc[gcol], o = sh[gcol];
#pragma unroll
        for (int r = 0; r < 4; r++) {
            float v = fmaxf(fmaf(acc[c][r], s, o), 0.f);
            Hout[(size_t)(nodebase + quad * 4 + r) * 128 + gcol] = f2bf(v);
        }
    }
}

// ---------------- GEMM: h0 = x @ W_in + b_in   ([N,64]x[64,128]) -> internal bf16
__global__ __launch_bounds__(256) void gemm_in_k(
    const void* __restrict__ X, const void* __restrict__ W,
    const void* __restrict__ bin, ushort_t* __restrict__ Hout,
    const int* __restrict__ flag)
{
    __shared__ ushort_t WT[128 * 72];
    int isb = flag[0];
    int tid = threadIdx.x;
    for (int idx = tid; idx < 64 * 128; idx += 256) {
        int k = idx >> 7, n = idx & 127;
        WT[n * 72 + k] = f2bf(ldf(W, idx, isb));
    }
    __syncthreads();
    int wave = tid >> 6, lane = tid & 63;
    int quad = lane >> 4, l16 = lane & 15;
    int row = blockIdx.x * 64 + wave * 16 + l16;

    f32x4 acc[8];
#pragma unroll
    for (int c = 0; c < 8; c++) acc[c] = (f32x4){0.f, 0.f, 0.f, 0.f};

#pragma unroll
    for (int kk = 0; kk < 2; kk++) {
        int aoff = row * 64 + kk * 32 + quad * 8;
        union { bf16x8 v; ushort_t s[8]; } a;
        if (isb) {
            a.v = *(const bf16x8*)((const ushort_t*)X + aoff);
        } else {
            const float* xf = (const float*)X + aoff;
            f32x4 p0 = *(const f32x4*)xf;
            f32x4 p1 = *(const f32x4*)(xf + 4);
#pragma unroll
            for (int j = 0; j < 4; j++) { a.s[j] = f2bf(p0[j]); a.s[4 + j] = f2bf(p1[j]); }
        }
#pragma unroll
        for (int c = 0; c < 8; c++) {
            bf16x8 b = *(const bf16x8*)(&WT[(c * 16 + l16) * 72 + kk * 32 + quad * 8]);
            acc[c] = __builtin_amdgcn_mfma_f32_16x16x32_bf16(a.v, b, acc[c], 0, 0, 0);
        }
    }
    int rbase = blockIdx.x * 64 + wave * 16 + quad * 4;
#pragma unroll
    for (int c = 0; c < 8; c++) {
        int gcol = c * 16 + l16;
        float bb = ldf(bin, gcol, isb);
#pragma unroll
        for (int r = 0; r < 4; r++) {
            Hout[(rbase + r) * 128 + gcol] = f2bf(acc[c][r] + bb);
        }
    }
}

// ---------------- pool
__global__ __launch_bounds__(128) void pool_k(
    const ushort_t* __restrict__ Hf, const int* __restrict__ batch,
    float* __restrict__ gsum, int* __restrict__ gcnt)
{
    int t = threadIdx.x;
    int n0 = blockIdx.x * 256;
    int n1 = n0 + 256;
    int cur = batch[n0];
    float s = 0.f; int c = 0;
    for (int n = n0; n < n1; n++) {
        int g = batch[n];
        if (g != cur) {
            atomicAdd(&gsum[cur * 128 + t], s);
            if (t == 0) atomicAdd(&gcnt[cur], c);
            s = 0.f; c = 0; cur = g;
        }
        s += bf2f(Hf[n * 128 + t]);
        c++;
    }
    atomicAdd(&gsum[cur * 128 + t], s);
    if (t == 0) atomicAdd(&gcnt[cur], c);
}

// ---------------- final
__global__ __launch_bounds__(128) void final_k(
    const float* __restrict__ gsum, const int* __restrict__ gcnt,
    const void* __restrict__ gx, const void* __restrict__ Wgp,
    const void* __restrict__ bgp, const void* __restrict__ Wgc,
    const void* __restrict__ bgc, void* __restrict__ out,
    const int* __restrict__ flag)
{
    __shared__ float gm[160];
    int isb = flag[0];
    int g = blockIdx.x, t = threadIdx.x;
    int c = gcnt[g]; if (c < 1) c = 1;
    gm[t] = gsum[g * 128 + t] / (float)c;
    if (t < 32) {
        float a = ldf(bgp, t, isb);
        for (int d = 0; d < 6; d++) a += ldf(gx, g * 6 + d, isb) * ldf(Wgp, d * 32 + t, isb);
        gm[128 + t] = fmaxf(a, 0.f);
    }
    __syncthreads();
    float a = ldf(bgc, t, isb);
    for (int k = 0; k < 160; k++) a += gm[k] * ldf(Wgc, k * 128 + t, isb);
    if (isb) ((ushort_t*)out)[g * 128 + t] = f2bf(a);
    else     ((float*)out)[g * 128 + t] = a;
}

extern "C" void kernel_launch(void* const* d_in, const int* in_sizes, int n_in,
                              void* d_out, int out_size, void* d_ws, size_t ws_size,
                              hipStream_t stream) {
    const void* x       = d_in[0];
    const void* ea_raw  = d_in[1];
    const void* gx      = d_in[2];
    const void* W_in    = d_in[3];
    const void* b_in    = d_in[4];
    const void* W_edge  = d_in[5];
    const void* b_edge  = d_in[6];
    const void* W_gcn   = d_in[7];
    const void* b_gcn   = d_in[8];
    const void* bn_g    = d_in[9];
    const void* bn_b    = d_in[10];
    const void* bn_m    = d_in[11];
    const void* bn_v    = d_in[12];
    const void* W_gproj = d_in[13];
    const void* b_gproj = d_in[14];
    const void* W_gcomb = d_in[15];
    const void* b_gcomb = d_in[16];
    const int* row   = (const int*)d_in[17];
    const int* col   = (const int*)d_in[18];
    const int* batch = (const int*)d_in[19];

    char* ws = (char*)d_ws;
    size_t off = 0;
    float*    gsum    = (float*)(ws + off);    off += (size_t)NG * HD * 4;
    int*      gcnt    = (int*)(ws + off);      off += 256;
    size_t zero_bytes = off;                    // [gsum|gcnt]
    int*      flag    = (int*)(ws + off);      off += 256;
    uint32_t* cntmat  = (uint32_t*)(ws + off); off += 256 * 256 * 4;
    uint32_t* offmat  = (uint32_t*)(ws + off); off += 256 * 256 * 4;
    uint32_t* btot    = (uint32_t*)(ws + off); off += 1024;
    uint32_t* bbase   = (uint32_t*)(ws + off); off += 1024;
    int*      csr_off = (int*)(ws + off);      off += (size_t)N_NODES * 4;
    int*      deg     = (int*)(ws + off);      off += (size_t)N_NODES * 4;
    ushort_t* wtg     = (ushort_t*)(ws + off); off += (size_t)NL * HD * HD * 2;
    float*    sc      = (float*)(ws + off);    off += (size_t)NL * HD * 4;
    float*    sh      = (float*)(ws + off);    off += (size_t)NL * HD * 4;
    uint2*    csr     = (uint2*)(ws + off);    off += (size_t)CSR_CAP * 8;
    ushort_t* hA      = (ushort_t*)(ws + off); off += (size_t)(N_NODES + 1) * HD * 2;
    ushort_t* hB      = (ushort_t*)(ws + off); off += (size_t)(N_NODES + 1) * HD * 2;
    uint2*    staged  = (uint2*)hB;  // overlay: staged (16.8MB) dead before layer0 writes hB

    hipMemsetAsync(ws, 0, zero_bytes, stream);
    hipMemsetAsync(hA + (size_t)N_NODES * HD, 0, HD * 2, stream);  // dummy row N
    hipMemsetAsync(hB + (size_t)N_NODES * HD, 0, HD * 2, stream);
    detect_k<<<1, 256, 0, stream>>>((const uint32_t*)ea_raw, flag);
    prep_bn<<<3, 128, 0, stream>>>(bn_g, bn_b, bn_m, bn_v, b_gcn, sc, sh, flag);
    transpose_k<<<(NL * HD * HD + 255) / 256, 256, 0, stream>>>(W_gcn, wtg, flag);

    bucketA_k<<<NCHUNK, 256, 0, stream>>>(row, col, ea_raw, staged, cntmat, offmat, flag);
    bucketsum_k<<<BUCKETS, 256, 0, stream>>>(cntmat, btot);
    scan2_k<<<1, 256, 0, stream>>>(btot, bbase);
    buildB_k<<<BUCKETS, 512, 0, stream>>>(staged, cntmat, offmat, bbase, csr, csr_off, deg);

    gemm_in_k<<<N_NODES / 64, 256, 0, stream>>>(x, W_in, b_in, hA, flag);

    ushort_t* hin = hA;
    ushort_t* hout = hB;
    for (int l = 0; l < NL; l++) {
        layer_fused_k<<<N_NODES / 64, 256, 0, stream>>>(
            (const uint32_t*)hin, csr_off, deg, csr,
            W_edge, b_edge, wtg + (size_t)l * HD * HD, sc + l * HD, sh + l * HD,
            hout, flag);
        ushort_t* tmp = hin; hin = hout; hout = tmp;
    }

    pool_k<<<N_NODES / 256, 128, 0, stream>>>(hin, batch, gsum, gcnt);
    final_k<<<NG, 128, 0, stream>>>(gsum, gcnt, gx, W_gproj, b_gproj,
                                    W_gcomb, b_gcomb, d_out, flag);
}

// Round 7
// 671.140 us; speedup vs baseline: 1.6720x; 1.0397x over previous
//
#include <hip/hip_runtime.h>
#include <stdint.h>

#define N_NODES 131072
#define N_EDGES 2097152
#define NG 64
#define HD 128
#define NL 3
#define EPSB 1e-5f

#define BUCKETS 256
#define BSHIFT 9               // 512 rows per bucket
#define ROWS_PB 512
#define CHUNK 8192             // edges per phase-A workgroup
#define NCHUNK (N_EDGES / CHUNK)   // 256
#define PAD_SLACK (7 * ROWS_PB)    // max pad8 slack per bucket = 3584
#define CSR_CAP (N_EDGES + BUCKETS * (PAD_SLACK + 8))
#define TPAD 68                // dword stride of per-wave LDS tile (16B aligned, 2-way banks)

typedef unsigned short ushort_t;
typedef __bf16 bf16x8 __attribute__((ext_vector_type(8)));
typedef float f32x4 __attribute__((ext_vector_type(4)));

__device__ __forceinline__ float bf2f(uint32_t u16) {
    union { uint32_t i; float f; } c; c.i = u16 << 16; return c.f;
}
__device__ __forceinline__ float lo2f(uint32_t u) {
    union { uint32_t i; float f; } c; c.i = u << 16; return c.f;
}
__device__ __forceinline__ float hi2f(uint32_t u) {
    union { uint32_t i; float f; } c; c.i = u & 0xffff0000u; return c.f;
}
__device__ __forceinline__ ushort_t f2bf(float f) {
    union { float f; uint32_t i; } c; c.f = f;
    uint32_t u = c.i;
    uint32_t r = (u + 0x7fffu + ((u >> 16) & 1u)) >> 16;
    return (ushort_t)r;
}
// dtype-adaptive scalar load: isb=1 -> bf16 array, isb=0 -> fp32 array
__device__ __forceinline__ float ldf(const void* p, int i, int isb) {
    return isb ? bf2f(((const ushort_t*)p)[i]) : ((const float*)p)[i];
}

// ---------------- dtype sniffer on edge_attr_raw
__global__ void detect_k(const uint32_t* __restrict__ ea, int* __restrict__ flag) {
    __shared__ int sm[256];
    int t = threadIdx.x;
    int plaus = 0;
    for (int j = 0; j < 16; j++) {
        uint32_t w = ea[t * 16 + j];
        uint32_t e0 = (w >> 7) & 0xFF;
        uint32_t e1 = (w >> 23) & 0xFF;
        plaus += (e0 >= 100 && e0 <= 140) ? 1 : 0;
        plaus += (e1 >= 100 && e1 <= 140) ? 1 : 0;
    }
    sm[t] = plaus;
    __syncthreads();
    for (int o = 128; o > 0; o >>= 1) {
        if (t < o) sm[t] += sm[t + o];
        __syncthreads();
    }
    if (t == 0) flag[0] = (sm[0] * 10 >= 8192 * 9) ? 1 : 0;
}

// ---------------- BN fold
__global__ void prep_bn(const void* gamma, const void* beta,
                        const void* mean, const void* var,
                        const void* bgcn, float* sc, float* sh,
                        const int* __restrict__ flag) {
    int isb = flag[0];
    int i = blockIdx.x * 128 + threadIdx.x;
    if (i < NL * HD) {
        float g = ldf(gamma, i, isb), b = ldf(beta, i, isb);
        float m = ldf(mean, i, isb), v = ldf(var, i, isb), bb = ldf(bgcn, i, isb);
        float s = g / sqrtf(v + EPSB);
        sc[i] = s;
        sh[i] = (bb - m) * s + b;
    }
}

// ---------------- pre-transpose W_gcn: WTg[l][n][k] = W[l][k][n], as bf16
__global__ void transpose_k(const void* __restrict__ W, ushort_t* __restrict__ WTg,
                            const int* __restrict__ flag) {
    int isb = flag[0];
    int idx = blockIdx.x * 256 + threadIdx.x;
    if (idx < NL * HD * HD) {
        int l = idx >> 14;
        int rem = idx & 16383;
        int k = rem >> 7, n = rem & 127;
        WTg[l * 16384 + n * 128 + k] = f2bf(ldf(W, idx, isb));
    }
}

// ---------------- Phase A: per-chunk bucket partition, XCD-exclusive writes
__global__ __launch_bounds__(256) void bucketA_k(
    const int* __restrict__ row, const int* __restrict__ col,
    const void* __restrict__ ea_raw,
    uint2* __restrict__ staged, uint32_t* __restrict__ cntmat,
    uint32_t* __restrict__ offmat, const int* __restrict__ flag)
{
    __shared__ int hist[256], offs[256], offs_ex[256], cur[256];
    int isb = flag[0];
    int t = threadIdx.x;
    int base = blockIdx.x * CHUNK;
    hist[t] = 0;
    __syncthreads();
#pragma unroll 4
    for (int j = 0; j < 32; j++) {
        int r = row[base + j * 256 + t];
        atomicAdd(&hist[r >> BSHIFT], 1);
    }
    __syncthreads();
    int v = hist[t];
    offs[t] = v;
    __syncthreads();
    for (int o = 1; o < 256; o <<= 1) {
        int u = (t >= o) ? offs[t - o] : 0;
        __syncthreads();
        offs[t] += u;
        __syncthreads();
    }
    offs_ex[t] = offs[t] - v;
    cur[t] = 0;
    cntmat[blockIdx.x * 256 + t] = (uint32_t)v;
    offmat[blockIdx.x * 256 + t] = (uint32_t)(offs[t] - v);
    __syncthreads();
    uint2* slice = staged + (size_t)blockIdx.x * CHUNK;
    for (int j = 0; j < 32; j++) {
        int e = base + j * 256 + t;
        int r = row[e];
        int b = r >> BSHIFT;
        uint32_t packed;
        if (isb) {
            packed = ((const uint32_t*)ea_raw)[e];
        } else {
            const float* f = (const float*)ea_raw + (size_t)e * 2;
            packed = (uint32_t)f2bf(f[0]) | ((uint32_t)f2bf(f[1]) << 16);
        }
        int pos = offs_ex[b] + atomicAdd(&cur[b], 1);
        slice[pos] = make_uint2((uint32_t)(((r & (ROWS_PB - 1)) << 17) | col[e]), packed);
    }
}

// ---------------- per-bucket totals
__global__ __launch_bounds__(256) void bucketsum_k(const uint32_t* __restrict__ cntmat,
                                                   uint32_t* __restrict__ btot) {
    __shared__ int sm[256];
    int b = blockIdx.x, t = threadIdx.x;
    sm[t] = (int)cntmat[t * 256 + b];
    __syncthreads();
    for (int o = 128; o > 0; o >>= 1) {
        if (t < o) sm[t] += sm[t + o];
        __syncthreads();
    }
    if (t == 0) btot[b] = (uint32_t)sm[0];
}

// ---------------- bucket bases. Capacity rounded to multiple of 8 so every
// bbase (hence every csr_off) is 8-entry aligned.
__global__ __launch_bounds__(256) void scan2_k(const uint32_t* __restrict__ btot,
                                               uint32_t* __restrict__ bbase) {
    __shared__ int sm[256];
    int t = threadIdx.x;
    int v = ((int)btot[t] + PAD_SLACK + 7) & ~7;
    sm[t] = v;
    __syncthreads();
    for (int o = 1; o < 256; o <<= 1) {
        int u = (t >= o) ? sm[t - o] : 0;
        __syncthreads();
        sm[t] += u;
        __syncthreads();
    }
    bbase[t] = (uint32_t)(sm[t] - v);
}

// ---------------- Phase B: one bucket per WG; build padded CSR span exclusively
__global__ __launch_bounds__(512) void buildB_k(
    const uint2* __restrict__ staged, const uint32_t* __restrict__ cntmat,
    const uint32_t* __restrict__ offmat, const uint32_t* __restrict__ bbase,
    uint2* __restrict__ csr, int* __restrict__ csr_off, int* __restrict__ deg)
{
    __shared__ int runoff[257];
    __shared__ int runstart[256];
    __shared__ int hist2[512];
    __shared__ int po[512];
    __shared__ int cur2[512];
    int b = blockIdx.x, t = threadIdx.x;

    int myc = 0;
    if (t < 256) {
        myc = (int)cntmat[t * 256 + b];
        runstart[t] = t * CHUNK + (int)offmat[t * 256 + b];
        runoff[t] = myc;
    }
    __syncthreads();
    for (int o = 1; o < 256; o <<= 1) {
        int u = 0;
        if (t < 256 && t >= o) u = runoff[t - o];
        __syncthreads();
        if (t < 256) runoff[t] += u;
        __syncthreads();
    }
    if (t < 256) {
        int incl = runoff[t];
        runoff[t] = incl - myc;
        if (t == 255) runoff[256] = incl;
    }
    hist2[t] = 0;
    cur2[t] = 0;
    __syncthreads();
    int T = runoff[256];

    for (int i = t; i < T; i += 512) {
        int lo = 0, hi = 255;
        while (lo < hi) { int mid = (lo + hi + 1) >> 1; if (runoff[mid] <= i) lo = mid; else hi = mid - 1; }
        uint32_t x = staged[runstart[lo] + (i - runoff[lo])].x;
        atomicAdd(&hist2[x >> 17], 1);
    }
    __syncthreads();

    int pv = (hist2[t] + 7) & ~7;
    po[t] = pv;
    __syncthreads();
    for (int o = 1; o < 512; o <<= 1) {
        int u = (t >= o) ? po[t - o] : 0;
        __syncthreads();
        po[t] += u;
        __syncthreads();
    }
    po[t] -= pv;
    __syncthreads();

    int gbase = (int)bbase[b];
    csr_off[b * ROWS_PB + t] = gbase + po[t];
    deg[b * ROWS_PB + t] = hist2[t];

    for (int i = t; i < T; i += 512) {
        int lo = 0, hi = 255;
        while (lo < hi) { int mid = (lo + hi + 1) >> 1; if (runoff[mid] <= i) lo = mid; else hi = mid - 1; }
        uint2 en = staged[runstart[lo] + (i - runoff[lo])];
        int r = en.x >> 17;
        int pos = po[r] + atomicAdd(&cur2[r], 1);
        csr[gbase + pos] = make_uint2(en.x & 0x1FFFFu, en.y);
    }
    __syncthreads();
    int d = hist2[t], p = (d + 7) & ~7;
    for (int k = d; k < p; k++) csr[gbase + po[t] + k] = make_uint2(N_NODES, 0u);
}

// ---------------- fused layer: ONE WAVE per block, 16 nodes, barrier-free.
// Per node: aggregate (2-group / 16-gather inner iterations) -> LDS tile,
// then 16x128 GEMM tile via MFMA + BN + ReLU.
__global__ __launch_bounds__(64, 4) void layer_fused_k(
    const uint32_t* __restrict__ h32,      // [N+1,64] u32 (bf16x2), row N zeroed
    const int* __restrict__ csr_off, const int* __restrict__ degv,
    const uint2* __restrict__ csr,
    const void* __restrict__ Wedge, const void* __restrict__ bedge,
    const ushort_t* __restrict__ WTg,      // [128][128] bf16, WT[n][k]
    const float* __restrict__ sc, const float* __restrict__ sh,
    ushort_t* __restrict__ Hout,           // [N+1][128] bf16
    const int* __restrict__ flag)
{
    __shared__ uint32_t tile[16 * TPAD];
    int isb = flag[0];
    int lane = threadIdx.x;
    int quad = lane >> 4, l16 = lane & 15;
    int nodebase = blockIdx.x * 16;

    float w0x = ldf(Wedge, 2 * lane, isb),       w0y = ldf(Wedge, 2 * lane + 1, isb);
    float w1x = ldf(Wedge, 128 + 2 * lane, isb), w1y = ldf(Wedge, 128 + 2 * lane + 1, isb);
    float bex = ldf(bedge, 2 * lane, isb),       bey = ldf(bedge, 2 * lane + 1, isb);

    int dg = degv[nodebase];
    int st = csr_off[nodebase];
    for (int i = 0; i < 16; i++) {
        int dgn = 0, stn = 0;
        if (i < 15) {                       // prefetch next node's meta
            dgn = degv[nodebase + i + 1];
            stn = csr_off[nodebase + i + 1];
        }
        uint32_t hn = h32[(uint32_t)(nodebase + i) * 64 + lane];  // own row, early

        int nit = (dg + 7) >> 3;
        const uint4* gp = (const uint4*)csr + (st >> 1);
        float ax = 0.f, ay = 0.f;
        int it = 0;
        for (; it + 2 <= nit; it += 2) {   // 16 gathers in flight
            uint4 q0 = gp[0], q1 = gp[1], q2 = gp[2], q3 = gp[3];
            uint4 q4 = gp[4], q5 = gp[5], q6 = gp[6], q7 = gp[7];
            gp += 8;
            uint32_t cols[16] = {q0.x, q0.z, q1.x, q1.z, q2.x, q2.z, q3.x, q3.z,
                                 q4.x, q4.z, q5.x, q5.z, q6.x, q6.z, q7.x, q7.z};
            uint32_t eav[16]  = {q0.y, q0.w, q1.y, q1.w, q2.y, q2.w, q3.y, q3.w,
                                 q4.y, q4.w, q5.y, q5.w, q6.y, q6.w, q7.y, q7.w};
            uint32_t hv[16];
#pragma unroll
            for (int j = 0; j < 16; j++) hv[j] = h32[cols[j] * 64 + lane];
#pragma unroll
            for (int j = 0; j < 16; j++) {
                float a0 = bf2f(eav[j] & 0xffffu);
                float a1 = bf2f(eav[j] >> 16);
                float ex = fmaf(a1, w1x, fmaf(a0, w0x, bex));
                float ey = fmaf(a1, w1y, fmaf(a0, w0y, bey));
                ax = fmaf(lo2f(hv[j]), ex, ax);
                ay = fmaf(hi2f(hv[j]), ey, ay);
            }
        }
        if (it < nit) {                    // tail group of 8
            uint4 q0 = gp[0], q1 = gp[1], q2 = gp[2], q3 = gp[3];
            uint32_t cols[8] = {q0.x, q0.z, q1.x, q1.z, q2.x, q2.z, q3.x, q3.z};
            uint32_t eav[8]  = {q0.y, q0.w, q1.y, q1.w, q2.y, q2.w, q3.y, q3.w};
            uint32_t hv[8];
#pragma unroll
            for (int j = 0; j < 8; j++) hv[j] = h32[cols[j] * 64 + lane];
#pragma unroll
            for (int j = 0; j < 8; j++) {
                float a0 = bf2f(eav[j] & 0xffffu);
                float a1 = bf2f(eav[j] >> 16);
                float ex = fmaf(a1, w1x, fmaf(a0, w0x, bex));
                float ey = fmaf(a1, w1y, fmaf(a0, w0y, bey));
                ax = fmaf(lo2f(hv[j]), ex, ax);
                ay = fmaf(hi2f(hv[j]), ey, ay);
            }
        }
        float inv = 1.0f / (float)(dg > 0 ? dg : 1);
        float tx = lo2f(hn) + ax * inv;
        float ty = hi2f(hn) + ay * inv;
        tile[i * TPAD + lane] = (uint32_t)f2bf(tx) | ((uint32_t)f2bf(ty) << 16);
        dg = dgn; st = stn;
    }
    // no barrier: single wave, own tile

    f32x4 acc[8];
#pragma unroll
    for (int c = 0; c < 8; c++) acc[c] = (f32x4){0.f, 0.f, 0.f, 0.f};

#pragma unroll
    for (int kk = 0; kk < 4; kk++) {
        bf16x8 a = *(const bf16x8*)(tile + l16 * TPAD + kk * 16 + quad * 4);
#pragma unroll
        for (int c = 0; c < 8; c++) {
            bf16x8 b = *(const bf16x8*)(WTg + (c * 16 + l16) * 128 + kk * 32 + quad * 8);
            acc[c] = __builtin_amdgcn_mfma_f32_16x16x32_bf16(a, b, acc[c], 0, 0, 0);
        }
    }
#pragma unroll
    for (int c = 0; c < 8; c++) {
        int gcol = c * 16 + l16;
        float s = sc[gcol], o = sh[gcol];
#pragma unroll
        for (int r = 0; r < 4; r++) {
            float v = fmaxf(fmaf(acc[c][r], s, o), 0.f);
            Hout[(size_t)(nodebase + quad * 4 + r) * 128 + gcol] = f2bf(v);
        }
    }
}

// ---------------- GEMM: h0 = x @ W_in + b_in   ([N,64]x[64,128]) -> internal bf16
__global__ __launch_bounds__(256) void gemm_in_k(
    const void* __restrict__ X, const void* __restrict__ W,
    const void* __restrict__ bin, ushort_t* __restrict__ Hout,
    const int* __restrict__ flag)
{
    __shared__ ushort_t WT[128 * 72];
    int isb = flag[0];
    int tid = threadIdx.x;
    for (int idx = tid; idx < 64 * 128; idx += 256) {
        int k = idx >> 7, n = idx & 127;
        WT[n * 72 + k] = f2bf(ldf(W, idx, isb));
    }
    __syncthreads();
    int wave = tid >> 6, lane = tid & 63;
    int quad = lane >> 4, l16 = lane & 15;
    int row = blockIdx.x * 64 + wave * 16 + l16;

    f32x4 acc[8];
#pragma unroll
    for (int c = 0; c < 8; c++) acc[c] = (f32x4){0.f, 0.f, 0.f, 0.f};

#pragma unroll
    for (int kk = 0; kk < 2; kk++) {
        int aoff = row * 64 + kk * 32 + quad * 8;
        union { bf16x8 v; ushort_t s[8]; } a;
        if (isb) {
            a.v = *(const bf16x8*)((const ushort_t*)X + aoff);
        } else {
            const float* xf = (const float*)X + aoff;
            f32x4 p0 = *(const f32x4*)xf;
            f32x4 p1 = *(const f32x4*)(xf + 4);
#pragma unroll
            for (int j = 0; j < 4; j++) { a.s[j] = f2bf(p0[j]); a.s[4 + j] = f2bf(p1[j]); }
        }
#pragma unroll
        for (int c = 0; c < 8; c++) {
            bf16x8 b = *(const bf16x8*)(&WT[(c * 16 + l16) * 72 + kk * 32 + quad * 8]);
            acc[c] = __builtin_amdgcn_mfma_f32_16x16x32_bf16(a.v, b, acc[c], 0, 0, 0);
        }
    }
    int rbase = blockIdx.x * 64 + wave * 16 + quad * 4;
#pragma unroll
    for (int c = 0; c < 8; c++) {
        int gcol = c * 16 + l16;
        float bb = ldf(bin, gcol, isb);
#pragma unroll
        for (int r = 0; r < 4; r++) {
            Hout[(rbase + r) * 128 + gcol] = f2bf(acc[c][r] + bb);
        }
    }
}

// ---------------- pool
__global__ __launch_bounds__(128) void pool_k(
    const ushort_t* __restrict__ Hf, const int* __restrict__ batch,
    float* __restrict__ gsum, int* __restrict__ gcnt)
{
    int t = threadIdx.x;
    int n0 = blockIdx.x * 256;
    int n1 = n0 + 256;
    int cur = batch[n0];
    float s = 0.f; int c = 0;
    for (int n = n0; n < n1; n++) {
        int g = batch[n];
        if (g != cur) {
            atomicAdd(&gsum[cur * 128 + t], s);
            if (t == 0) atomicAdd(&gcnt[cur], c);
            s = 0.f; c = 0; cur = g;
        }
        s += bf2f(Hf[n * 128 + t]);
        c++;
    }
    atomicAdd(&gsum[cur * 128 + t], s);
    if (t == 0) atomicAdd(&gcnt[cur], c);
}

// ---------------- final
__global__ __launch_bounds__(128) void final_k(
    const float* __restrict__ gsum, const int* __restrict__ gcnt,
    const void* __restrict__ gx, const void* __restrict__ Wgp,
    const void* __restrict__ bgp, const void* __restrict__ Wgc,
    const void* __restrict__ bgc, void* __restrict__ out,
    const int* __restrict__ flag)
{
    __shared__ float gm[160];
    int isb = flag[0];
    int g = blockIdx.x, t = threadIdx.x;
    int c = gcnt[g]; if (c < 1) c = 1;
    gm[t] = gsum[g * 128 + t] / (float)c;
    if (t < 32) {
        float a = ldf(bgp, t, isb);
        for (int d = 0; d < 6; d++) a += ldf(gx, g * 6 + d, isb) * ldf(Wgp, d * 32 + t, isb);
        gm[128 + t] = fmaxf(a, 0.f);
    }
    __syncthreads();
    float a = ldf(bgc, t, isb);
    for (int k = 0; k < 160; k++) a += gm[k] * ldf(Wgc, k * 128 + t, isb);
    if (isb) ((ushort_t*)out)[g * 128 + t] = f2bf(a);
    else     ((float*)out)[g * 128 + t] = a;
}

extern "C" void kernel_launch(void* const* d_in, const int* in_sizes, int n_in,
                              void* d_out, int out_size, void* d_ws, size_t ws_size,
                              hipStream_t stream) {
    const void* x       = d_in[0];
    const void* ea_raw  = d_in[1];
    const void* gx      = d_in[2];
    const void* W_in    = d_in[3];
    const void* b_in    = d_in[4];
    const void* W_edge  = d_in[5];
    const void* b_edge  = d_in[6];
    const void* W_gcn   = d_in[7];
    const void* b_gcn   = d_in[8];
    const void* bn_g    = d_in[9];
    const void* bn_b    = d_in[10];
    const void* bn_m    = d_in[11];
    const void* bn_v    = d_in[12];
    const void* W_gproj = d_in[13];
    const void* b_gproj = d_in[14];
    const void* W_gcomb = d_in[15];
    const void* b_gcomb = d_in[16];
    const int* row   = (const int*)d_in[17];
    const int* col   = (const int*)d_in[18];
    const int* batch = (const int*)d_in[19];

    char* ws = (char*)d_ws;
    size_t off = 0;
    float*    gsum    = (float*)(ws + off);    off += (size_t)NG * HD * 4;
    int*      gcnt    = (int*)(ws + off);      off += 256;
    size_t zero_bytes = off;                    // [gsum|gcnt]
    int*      flag    = (int*)(ws + off);      off += 256;
    uint32_t* cntmat  = (uint32_t*)(ws + off); off += 256 * 256 * 4;
    uint32_t* offmat  = (uint32_t*)(ws + off); off += 256 * 256 * 4;
    uint32_t* btot    = (uint32_t*)(ws + off); off += 1024;
    uint32_t* bbase   = (uint32_t*)(ws + off); off += 1024;
    int*      csr_off = (int*)(ws + off);      off += (size_t)N_NODES * 4;
    int*      deg     = (int*)(ws + off);      off += (size_t)N_NODES * 4;
    ushort_t* wtg     = (ushort_t*)(ws + off); off += (size_t)NL * HD * HD * 2;
    float*    sc      = (float*)(ws + off);    off += (size_t)NL * HD * 4;
    float*    sh      = (float*)(ws + off);    off += (size_t)NL * HD * 4;
    uint2*    csr     = (uint2*)(ws + off);    off += (size_t)CSR_CAP * 8;
    ushort_t* hA      = (ushort_t*)(ws + off); off += (size_t)(N_NODES + 1) * HD * 2;
    ushort_t* hB      = (ushort_t*)(ws + off); off += (size_t)(N_NODES + 1) * HD * 2;
    uint2*    staged  = (uint2*)hB;  // overlay: staged (16.8MB) dead before layer0 writes hB

    hipMemsetAsync(ws, 0, zero_bytes, stream);
    hipMemsetAsync(hA + (size_t)N_NODES * HD, 0, HD * 2, stream);  // dummy row N
    hipMemsetAsync(hB + (size_t)N_NODES * HD, 0, HD * 2, stream);
    detect_k<<<1, 256, 0, stream>>>((const uint32_t*)ea_raw, flag);
    prep_bn<<<3, 128, 0, stream>>>(bn_g, bn_b, bn_m, bn_v, b_gcn, sc, sh, flag);
    transpose_k<<<(NL * HD * HD + 255) / 256, 256, 0, stream>>>(W_gcn, wtg, flag);

    bucketA_k<<<NCHUNK, 256, 0, stream>>>(row, col, ea_raw, staged, cntmat, offmat, flag);
    bucketsum_k<<<BUCKETS, 256, 0, stream>>>(cntmat, btot);
    scan2_k<<<1, 256, 0, stream>>>(btot, bbase);
    buildB_k<<<BUCKETS, 512, 0, stream>>>(staged, cntmat, offmat, bbase, csr, csr_off, deg);

    gemm_in_k<<<N_NODES / 64, 256, 0, stream>>>(x, W_in, b_in, hA, flag);

    ushort_t* hin = hA;
    ushort_t* hout = hB;
    for (int l = 0; l < NL; l++) {
        layer_fused_k<<<N_NODES / 16, 64, 0, stream>>>(
            (const uint32_t*)hin, csr_off, deg, csr,
            W_edge, b_edge, wtg + (size_t)l * HD * HD, sc + l * HD, sh + l * HD,
            hout, flag);
        ushort_t* tmp = hin; hin = hout; hout = tmp;
    }

    pool_k<<<N_NODES / 256, 128, 0, stream>>>(hin, batch, gsum, gcnt);
    final_k<<<NG, 128, 0, stream>>>(gsum, gcnt, gx, W_gproj, b_gproj,
                                    W_gcomb, b_gcomb, d_out, flag);
}